// Round 1
// baseline (844.412 us; speedup 1.0000x reference)
//
#include <hip/hip_runtime.h>
#include <math.h>

#define HW 65536
#define TH_ 0.024543692606170259f  // 2*pi/256

__device__ __forceinline__ float gelu_f(float v){
    return 0.5f*v*(1.0f + erff(v*0.7071067811865476f));
}

// GH[h] = sum_{ky<16} e^{-2pi i ky h /256}
__global__ void k_tables(float* __restrict__ GH){
    int h = threadIdx.x;
    double gr = 0.0, gi = 0.0;
    for (int ky=0; ky<16; ++ky){
        double a = -2.0*3.14159265358979323846*(double)(ky*h)/256.0;
        gr += cos(a); gi += sin(a);
    }
    GH[2*h] = (float)gr; GH[2*h+1] = (float)gi;
}

// x[b,c,hw] = gelu(sum_i lw[c,i]*state[b,i,hw] + lb[c])
__global__ __launch_bounds__(256) void k_lift(const float* __restrict__ st, const float* __restrict__ lw,
                                              const float* __restrict__ lb, float* __restrict__ x){
    int p = blockIdx.x*256 + threadIdx.x;
    int b = p >> 16, hw = p & (HW-1);
    float s0 = st[(b*3+0)*HW + hw];
    float s1 = st[(b*3+1)*HW + hw];
    float s2 = st[(b*3+2)*HW + hw];
    float* xp = x + (size_t)b*64*HW + hw;
    for (int c=0;c<64;++c){
        float v = fmaf(lw[c*3], s0, fmaf(lw[c*3+1], s1, fmaf(lw[c*3+2], s2, lb[c])));
        xp[(size_t)c*HW] = gelu_f(v);
    }
}

// S[b,i,k] = (1/256) sum_w e^{-i th k w} * (sum_h GH[h]*x[b,i,h,w])
__global__ __launch_bounds__(256) void k_analysis(const float* __restrict__ x, const float* __restrict__ GH,
                                                  float* __restrict__ S){
    int b = blockIdx.x >> 6, i = blockIdx.x & 63;
    int w = threadIdx.x;
    const float* xp = x + ((size_t)(b*64+i))*HW + w;
    float Tr = 0.f, Ti = 0.f;
    #pragma unroll 4
    for (int h=0; h<256; ++h){
        float v = xp[h*256];
        Tr = fmaf(GH[2*h],   v, Tr);
        Ti = fmaf(GH[2*h+1], v, Ti);
    }
    float c1, s1; sincosf((float)w * TH_, &s1, &c1);
    float Sr[16], Si[16];
    float ck = 1.f, sk = 0.f;
    #pragma unroll
    for (int k=0;k<16;++k){
        Sr[k] = Tr*ck + Ti*sk;     // T * e^{-i th k w}
        Si[k] = Ti*ck - Tr*sk;
        float nc = ck*c1 - sk*s1;
        sk = ck*s1 + sk*c1;
        ck = nc;
    }
    #pragma unroll
    for (int k=0;k<16;++k){
        #pragma unroll
        for (int off=32; off; off>>=1){
            Sr[k] += __shfl_xor(Sr[k], off, 64);
            Si[k] += __shfl_xor(Si[k], off, 64);
        }
    }
    __shared__ float red[4][32];
    int wv = threadIdx.x >> 6, ln = threadIdx.x & 63;
    if (ln == 0){
        #pragma unroll
        for (int k=0;k<16;++k){ red[wv][2*k] = Sr[k]; red[wv][2*k+1] = Si[k]; }
    }
    __syncthreads();
    if (threadIdx.x < 32){
        float v = red[0][threadIdx.x]+red[1][threadIdx.x]+red[2][threadIdx.x]+red[3][threadIdx.x];
        S[(b*64+i)*32 + threadIdx.x] = v * (1.0f/256.0f);
    }
}

// A[b,j,km] = sum_i S[b,i,k] * (wr + i wi)[i,j,km]
__global__ __launch_bounds__(256) void k_mixA(const float* __restrict__ S, const float* __restrict__ wr,
                                              const float* __restrict__ wi, float* __restrict__ A){
    int j = blockIdx.x >> 3, b = blockIdx.x & 7;
    __shared__ float sS[2048];
    for (int t=threadIdx.x; t<2048; t+=256) sS[t] = S[b*2048 + t];
    __syncthreads();
    int km = threadIdx.x, k = km >> 4;
    float ar = 0.f, ai = 0.f;
    const float* wrp = wr + j*256 + km;
    const float* wip = wi + j*256 + km;
    #pragma unroll 4
    for (int i=0;i<64;++i){
        float wrv = wrp[i*16384];
        float wiv = wip[i*16384];
        float2 sv = ((const float2*)sS)[i*16 + k];
        ar += sv.x*wrv - sv.y*wiv;
        ai += sv.x*wiv + sv.y*wrv;
    }
    ((float2*)A)[(b*64 + j)*256 + km] = make_float2(ar, ai);
}

// c = sum_j pw[o,j]*A[b,j,km]; Parseval instance-norm stats; CS = c * inv_sigma * alpha(m) / 256
__global__ __launch_bounds__(256) void k_mixB(const float* __restrict__ A, const float* __restrict__ pw,
                                              float* __restrict__ CS){
    int b = blockIdx.x >> 6, o = blockIdx.x & 63;
    int km = threadIdx.x, m = km & 15;
    const float2* Ap = (const float2*)A + b*64*256 + km;
    const float* pwp = pw + o*64;
    float cr=0.f, ci=0.f;
    #pragma unroll 4
    for (int j=0;j<64;++j){
        float p = pwp[j];
        float2 a = Ap[j*256];
        cr = fmaf(p, a.x, cr);
        ci = fmaf(p, a.y, ci);
    }
    float aw = (m==0)? 1.f : 4.f;          // alpha(m)^2
    float s = (km==0)? 0.f : aw*(cr*cr + ci*ci);
    #pragma unroll
    for (int off=32; off; off>>=1) s += __shfl_xor(s, off, 64);
    __shared__ float rsum[4];
    __shared__ float sinv;
    if ((threadIdx.x & 63) == 0) rsum[threadIdx.x>>6] = s;
    __syncthreads();
    if (threadIdx.x == 0){
        float var = (rsum[0]+rsum[1]+rsum[2]+rsum[3]) * (1.0f/131072.0f); // /(2*H*W)
        sinv = rsqrtf(var + 1e-5f);
    }
    __syncthreads();
    float alpha = (m==0)? 1.f : 2.f;
    float sc = sinv * alpha * (1.0f/256.0f);
    if (km == 0) cr = 0.f;                 // remove mean (DC real part)
    ((float2*)CS)[blockIdx.x*256 + km] = make_float2(cr*sc, ci*sc);
}

// x[b,o,h,w] = gelu( sum_k Re( V_k(w) e^{+i th k h} ) ) + x[b,o,h,w]
__global__ __launch_bounds__(256) void k_synth(const float* __restrict__ CS, float* __restrict__ x){
    int bo = blockIdx.x >> 2, wt = blockIdx.x & 3;
    int lane = threadIdx.x & 63, wv = threadIdx.x >> 6;
    int w = wt*64 + lane;
    const float2* cs = (const float2*)CS + bo*256;
    float Vr[16], Vi[16];
    {
        float stepc, steps; sincosf((float)w*TH_, &steps, &stepc);
        #pragma unroll
        for (int k=0;k<16;++k){ float2 a = cs[k*16]; Vr[k]=a.x; Vi[k]=a.y; }
        float pc = stepc, ps = steps;      // e^{+i m th w}, m=1
        for (int m=1;m<16;++m){
            #pragma unroll
            for (int k=0;k<16;++k){
                float2 a = cs[k*16+m];
                Vr[k] += a.x*pc - a.y*ps;
                Vi[k] += a.x*ps + a.y*pc;
            }
            float nc = pc*stepc - ps*steps;
            ps = pc*steps + ps*stepc;
            pc = nc;
        }
    }
    int h0 = wv*16;
    float rc[16], rs[16], qr[16], qi[16];
    #pragma unroll
    for (int k=0;k<16;++k){
        sincosf((float)k*TH_, &rs[k], &rc[k]);
        float c0, s0; sincosf((float)(k*h0)*TH_, &s0, &c0);
        qr[k] = Vr[k]*c0 - Vi[k]*s0;       // q = V * e^{+i th k h0}
        qi[k] = Vr[k]*s0 + Vi[k]*c0;
    }
    float* xp = x + ((size_t)bo << 16);
    for (int i=0;i<16;++i){
        float y0=0.f,y1=0.f,y2=0.f,y3=0.f;
        #pragma unroll
        for (int k=0;k<16;++k){
            float re = qr[k], im = qi[k];
            y0 += re;                                   // h
            if ((k&3)==0)      { y1 += re; y2 += re; y3 += re; }   // *i^k, *(-1)^k, *(-i)^k
            else if ((k&3)==1) { y1 -= im; y2 -= re; y3 += im; }
            else if ((k&3)==2) { y1 -= re; y2 += re; y3 -= re; }
            else               { y1 += im; y2 -= re; y3 -= im; }
        }
        #pragma unroll
        for (int k=1;k<16;++k){
            float nr = qr[k]*rc[k] - qi[k]*rs[k];
            qi[k]    = qr[k]*rs[k] + qi[k]*rc[k];
            qr[k] = nr;
        }
        int p0 = (h0+i)*256 + w;
        float x0 = xp[p0], x1 = xp[p0+16384], x2 = xp[p0+32768], x3 = xp[p0+49152];
        xp[p0]       = gelu_f(y0) + x0;
        xp[p0+16384] = gelu_f(y1) + x1;
        xp[p0+32768] = gelu_f(y2) + x2;
        xp[p0+49152] = gelu_f(y3) + x3;
    }
}

__global__ __launch_bounds__(256) void k_heads(const float* __restrict__ x,
        const float* __restrict__ fw1, const float* __restrict__ fb1,
        const float* __restrict__ fw2, const float* __restrict__ fb2,
        const float* __restrict__ qw1, const float* __restrict__ qb1,
        const float* __restrict__ qw2, const float* __restrict__ qb2,
        float* __restrict__ J, float* __restrict__ dtP){
    int p = blockIdx.x*256 + threadIdx.x;
    int b = p >> 16, hw = p & (HW-1);
    const float* xp = x + (size_t)b*64*HW + hw;
    float xv[64];
    #pragma unroll
    for (int c=0;c<64;++c) xv[c] = xp[(size_t)c*HW];
    float J0=fb2[0], J1=fb2[1], P0=qb2[0], P1=qb2[1];
    for (int c=0;c<64;++c){
        float a1 = fb1[c], a2 = qb1[c];
        #pragma unroll
        for (int i=0;i<64;++i){
            a1 = fmaf(fw1[c*64+i], xv[i], a1);
            a2 = fmaf(qw1[c*64+i], xv[i], a2);
        }
        a1 = gelu_f(a1); a2 = gelu_f(a2);
        J0 = fmaf(fw2[c],    a1, J0);
        J1 = fmaf(fw2[64+c], a1, J1);
        P0 = fmaf(qw2[c],    a2, P0);
        P1 = fmaf(qw2[64+c], a2, P1);
    }
    J[(size_t)(b*2+0)*HW + hw] = J0;
    J[(size_t)(b*2+1)*HW + hw] = J1;
    dtP[(size_t)(b*2+0)*HW + hw] = P0;
    dtP[(size_t)(b*2+1)*HW + hw] = P1;
}

// F1[b,f,h,kx] = (1/16) sum_w J[row,w] e^{-i th kx w}
__global__ __launch_bounds__(256) void k_rfftW(const float* __restrict__ J, float* __restrict__ F1x, float* __restrict__ F1y){
    int row = blockIdx.x;             // (b*2+f)*256 + h
    int kx = threadIdx.x;
    if (kx < 129){
        const float* rp = J + (size_t)row*256;
        float sc, ss; sincosf((float)kx*TH_, &ss, &sc);
        float pr=1.f, pi=0.f;          // e^{-i th kx w}
        float ar=0.f, ai=0.f;
        for (int w=0; w<256; ++w){
            float v = rp[w];
            ar = fmaf(v, pr, ar);
            ai = fmaf(v, pi, ai);
            float nr = pr*sc + pi*ss;   // * (sc - i ss)
            pi = pi*sc - pr*ss;
            pr = nr;
        }
        int f = (row >> 8) & 1;
        int bh = ((row >> 9) << 8) | (row & 255);
        float2* outp = (float2*)(f ? F1y : F1x) + (size_t)bh*129 + kx;
        *outp = make_float2(ar*(1.f/16.f), ai*(1.f/16.f));
    }
}

// F2[b,ky,kx] = (1/16)( i*fy(ky)*fftH(F1x) + i*fx(kx)*fftH(F1y) )
__global__ __launch_bounds__(256) void k_fftHdiv(const float* __restrict__ F1x, const float* __restrict__ F1y, float* __restrict__ F2){
    int b = blockIdx.x / 129, kx = blockIdx.x % 129;
    int ky = threadIdx.x;
    const float2* px = (const float2*)F1x + (size_t)b*256*129 + kx;
    const float2* py = (const float2*)F1y + (size_t)b*256*129 + kx;
    float sc, ss; sincosf((float)ky*TH_, &ss, &sc);
    float pr=1.f, pi=0.f;              // e^{-i th ky h}
    float xr=0.f,xi=0.f,yr=0.f,yi=0.f;
    for (int h=0; h<256; ++h){
        float2 vx = px[(size_t)h*129];
        float2 vy = py[(size_t)h*129];
        xr += vx.x*pr - vx.y*pi;  xi += vx.x*pi + vx.y*pr;
        yr += vy.x*pr - vy.y*pi;  yi += vy.x*pi + vy.y*pr;
        float nr = pr*sc + pi*ss; pi = pi*sc - pr*ss; pr = nr;
    }
    float fy = (ky < 128)? (float)ky : (float)(ky-256);
    float fx = (kx < 128)? (float)kx : -128.f;
    float dr = -(fy*xi + fx*yi) * (1.f/16.f);
    float di =  (fy*xr + fx*yr) * (1.f/16.f);
    ((float2*)F2)[(size_t)(b*256+ky)*129 + kx] = make_float2(dr, di);
}

// F3[b,h,kx] = (1/16) sum_ky F2 e^{+i th ky h}
__global__ __launch_bounds__(256) void k_ifftH(const float* __restrict__ F2, float* __restrict__ F3){
    int b = blockIdx.x / 129, kx = blockIdx.x % 129;
    int h = threadIdx.x;
    const float2* p2 = (const float2*)F2 + (size_t)b*256*129 + kx;
    float sc, ss; sincosf((float)h*TH_, &ss, &sc);
    float pr=1.f, pi=0.f;
    float arr=0.f, aii=0.f;
    for (int ky=0; ky<256; ++ky){
        float2 v = p2[(size_t)ky*129];
        arr += v.x*pr - v.y*pi;
        aii += v.x*pi + v.y*pr;
        float nr = pr*sc - pi*ss; pi = pi*sc + pr*ss; pr = nr;  // * (sc + i ss)
    }
    ((float2*)F3)[(size_t)(b*256+h)*129 + kx] = make_float2(arr*(1.f/16.f), aii*(1.f/16.f));
}

// dt_rho = -irfftW(F3); write pred rho (softplus10) and dt rho channels
__global__ __launch_bounds__(256) void k_irfftW(const float* __restrict__ F3, const float* __restrict__ st, float* __restrict__ outp){
    int b = blockIdx.x >> 8, h = blockIdx.x & 255;
    int w = threadIdx.x;
    const float2* rp = (const float2*)F3 + (size_t)(b*256+h)*129;
    float sc, ss; sincosf((float)w*TH_, &ss, &sc);
    float2 b0 = rp[0];
    float y = b0.x;
    float pr = sc, pi = ss;            // kx=1 phase e^{+i th w}
    for (int kx=1; kx<128; ++kx){
        float2 v = rp[kx];
        y += 2.f*(v.x*pr - v.y*pi);
        float nr = pr*sc - pi*ss; pi = pi*sc + pr*ss; pr = nr;
    }
    float2 v128 = rp[128];
    y += (w & 1)? -v128.x : v128.x;
    y *= (1.f/16.f);
    float rho = -y;
    int hw = h*256 + w;
    float s0 = st[(size_t)(b*3)*HW + hw];
    float t = 10.f*fmaf(0.05f, rho, s0);
    float sp = fmaxf(t, 0.f) + log1pf(expf(-fabsf(t)));
    outp[(size_t)(b*3)*HW + hw] = 0.1f*sp;
    outp[(size_t)1572864 + (size_t)(b*3)*HW + hw] = rho;
}

__global__ __launch_bounds__(256) void k_final(const float* __restrict__ dtP, const float* __restrict__ st, float* __restrict__ outp){
    int idx = blockIdx.x*256 + threadIdx.x;   // (b*2+c)*HW + hw
    int b = idx >> 17, r = idx & (2*HW-1);
    int c = r >> 16, hw = r & (HW-1);
    float dp = dtP[idx];
    float sv = st[(size_t)(b*3+1+c)*HW + hw];
    outp[(size_t)(b*3+1+c)*HW + hw] = fmaf(0.05f, dp, sv);
    outp[(size_t)1572864 + (size_t)(b*3+1+c)*HW + hw] = dp;
}

extern "C" void kernel_launch(void* const* d_in, const int* in_sizes, int n_in,
                              void* d_out, int out_size, void* d_ws, size_t ws_size,
                              hipStream_t stream){
    const float* state = (const float*)d_in[0];
    const float* lw  = (const float*)d_in[1];
    const float* lb  = (const float*)d_in[2];
    const float* swr = (const float*)d_in[3];
    const float* swi = (const float*)d_in[4];
    const float* pww = (const float*)d_in[5];
    // d_in[6] = pw_b : cancels exactly in InstanceNorm, unused
    const float* fw1 = (const float*)d_in[7];
    const float* fb1 = (const float*)d_in[8];
    const float* fw2 = (const float*)d_in[9];
    const float* fb2 = (const float*)d_in[10];
    const float* qw1 = (const float*)d_in[11];
    const float* qb1 = (const float*)d_in[12];
    const float* qw2 = (const float*)d_in[13];
    const float* qb2 = (const float*)d_in[14];
    float* outp = (float*)d_out;
    float* ws = (float*)d_ws;

    float* x   = ws;                    // 33,554,432 f32
    float* S   = x   + 33554432;        // 16,384
    float* A   = S   + 16384;           // 262,144
    float* CS  = A   + 262144;          // 262,144
    float* J   = CS  + 262144;          // 1,048,576
    float* dtP = J   + 1048576;         // 1,048,576
    float* F1x = dtP + 1048576;         // 528,384
    float* F1y = F1x + 528384;          // 528,384
    float* F2  = F1y + 528384;          // 528,384
    float* F3  = F2  + 528384;          // 528,384
    float* GH  = F3  + 528384;          // 512

    hipLaunchKernelGGL(k_tables, dim3(1), dim3(256), 0, stream, GH);
    hipLaunchKernelGGL(k_lift, dim3(2048), dim3(256), 0, stream, state, lw, lb, x);
    for (int l=0; l<4; ++l){
        hipLaunchKernelGGL(k_analysis, dim3(512), dim3(256), 0, stream, x, GH, S);
        hipLaunchKernelGGL(k_mixA, dim3(512), dim3(256), 0, stream, S,
                           swr + (size_t)l*1048576, swi + (size_t)l*1048576, A);
        hipLaunchKernelGGL(k_mixB, dim3(512), dim3(256), 0, stream, A, pww + l*4096, CS);
        hipLaunchKernelGGL(k_synth, dim3(2048), dim3(256), 0, stream, CS, x);
    }
    hipLaunchKernelGGL(k_heads, dim3(2048), dim3(256), 0, stream, x,
                       fw1, fb1, fw2, fb2, qw1, qb1, qw2, qb2, J, dtP);
    hipLaunchKernelGGL(k_rfftW,  dim3(4096), dim3(256), 0, stream, J, F1x, F1y);
    hipLaunchKernelGGL(k_fftHdiv, dim3(1032), dim3(256), 0, stream, F1x, F1y, F2);
    hipLaunchKernelGGL(k_ifftH,  dim3(1032), dim3(256), 0, stream, F2, F3);
    hipLaunchKernelGGL(k_irfftW, dim3(2048), dim3(256), 0, stream, F3, state, outp);
    hipLaunchKernelGGL(k_final,  dim3(4096), dim3(256), 0, stream, dtP, state, outp);
}

// Round 2
// 838.821 us; speedup vs baseline: 1.0067x; 1.0067x over previous
//
#include <hip/hip_runtime.h>
#include <math.h>

#define HW 65536
#define TH_ 0.024543692606170259f  // 2*pi/256

__device__ __forceinline__ float gelu_f(float v){
    return 0.5f*v*(1.0f + erff(v*0.7071067811865476f));
}

// GH[h] = sum_{ky<16} e^{-2pi i ky h /256}
__global__ void k_tables(float* __restrict__ GH){
    int h = threadIdx.x;
    double gr = 0.0, gi = 0.0;
    for (int ky=0; ky<16; ++ky){
        double a = -2.0*3.14159265358979323846*(double)(ky*h)/256.0;
        gr += cos(a); gi += sin(a);
    }
    GH[2*h] = (float)gr; GH[2*h+1] = (float)gi;
}

// x[b,c,hw] = gelu(sum_i lw[c,i]*state[b,i,hw] + lb[c])
__global__ __launch_bounds__(256) void k_lift(const float* __restrict__ st, const float* __restrict__ lw,
                                              const float* __restrict__ lb, float* __restrict__ x){
    int p = blockIdx.x*256 + threadIdx.x;
    int b = p >> 16, hw = p & (HW-1);
    float s0 = st[(b*3+0)*HW + hw];
    float s1 = st[(b*3+1)*HW + hw];
    float s2 = st[(b*3+2)*HW + hw];
    float* xp = x + (size_t)b*64*HW + hw;
    for (int c=0;c<64;++c){
        float v = fmaf(lw[c*3], s0, fmaf(lw[c*3+1], s1, fmaf(lw[c*3+2], s2, lb[c])));
        xp[(size_t)c*HW] = gelu_f(v);
    }
}

// S[b,i,k] = (1/256) sum_w e^{-i th k w} * (sum_h GH[h]*x[b,i,h,w])
__global__ __launch_bounds__(256) void k_analysis(const float* __restrict__ x, const float* __restrict__ GH,
                                                  float* __restrict__ S){
    int b = blockIdx.x >> 6, i = blockIdx.x & 63;
    int w = threadIdx.x;
    const float* xp = x + ((size_t)(b*64+i))*HW + w;
    float Tr = 0.f, Ti = 0.f;
    #pragma unroll 4
    for (int h=0; h<256; ++h){
        float v = xp[h*256];
        Tr = fmaf(GH[2*h],   v, Tr);
        Ti = fmaf(GH[2*h+1], v, Ti);
    }
    float c1, s1; sincosf((float)w * TH_, &s1, &c1);
    float Sr[16], Si[16];
    float ck = 1.f, sk = 0.f;
    #pragma unroll
    for (int k=0;k<16;++k){
        Sr[k] = Tr*ck + Ti*sk;     // T * e^{-i th k w}
        Si[k] = Ti*ck - Tr*sk;
        float nc = ck*c1 - sk*s1;
        sk = ck*s1 + sk*c1;
        ck = nc;
    }
    #pragma unroll
    for (int k=0;k<16;++k){
        #pragma unroll
        for (int off=32; off; off>>=1){
            Sr[k] += __shfl_xor(Sr[k], off, 64);
            Si[k] += __shfl_xor(Si[k], off, 64);
        }
    }
    __shared__ float red[4][32];
    int wv = threadIdx.x >> 6, ln = threadIdx.x & 63;
    if (ln == 0){
        #pragma unroll
        for (int k=0;k<16;++k){ red[wv][2*k] = Sr[k]; red[wv][2*k+1] = Si[k]; }
    }
    __syncthreads();
    if (threadIdx.x < 32){
        float v = red[0][threadIdx.x]+red[1][threadIdx.x]+red[2][threadIdx.x]+red[3][threadIdx.x];
        S[(b*64+i)*32 + threadIdx.x] = v * (1.0f/256.0f);
    }
}

// A[b,j,km] = sum_i S[b,i,k] * (wr + i wi)[i,j,km]
__global__ __launch_bounds__(256) void k_mixA(const float* __restrict__ S, const float* __restrict__ wr,
                                              const float* __restrict__ wi, float* __restrict__ A){
    int j = blockIdx.x >> 3, b = blockIdx.x & 7;
    __shared__ float sS[2048];
    for (int t=threadIdx.x; t<2048; t+=256) sS[t] = S[b*2048 + t];
    __syncthreads();
    int km = threadIdx.x, k = km >> 4;
    float ar = 0.f, ai = 0.f;
    const float* wrp = wr + j*256 + km;
    const float* wip = wi + j*256 + km;
    #pragma unroll 4
    for (int i=0;i<64;++i){
        float wrv = wrp[i*16384];
        float wiv = wip[i*16384];
        float2 sv = ((const float2*)sS)[i*16 + k];
        ar += sv.x*wrv - sv.y*wiv;
        ai += sv.x*wiv + sv.y*wrv;
    }
    ((float2*)A)[(b*64 + j)*256 + km] = make_float2(ar, ai);
}

// c = sum_j pw[o,j]*A[b,j,km]; Parseval instance-norm stats; CS = c * inv_sigma * alpha(m) / 256
__global__ __launch_bounds__(256) void k_mixB(const float* __restrict__ A, const float* __restrict__ pw,
                                              float* __restrict__ CS){
    int b = blockIdx.x >> 6, o = blockIdx.x & 63;
    int km = threadIdx.x, m = km & 15;
    const float2* Ap = (const float2*)A + b*64*256 + km;
    const float* pwp = pw + o*64;
    float cr=0.f, ci=0.f;
    #pragma unroll 4
    for (int j=0;j<64;++j){
        float p = pwp[j];
        float2 a = Ap[j*256];
        cr = fmaf(p, a.x, cr);
        ci = fmaf(p, a.y, ci);
    }
    float aw = (m==0)? 1.f : 4.f;          // alpha(m)^2
    float s = (km==0)? 0.f : aw*(cr*cr + ci*ci);
    #pragma unroll
    for (int off=32; off; off>>=1) s += __shfl_xor(s, off, 64);
    __shared__ float rsum[4];
    __shared__ float sinv;
    if ((threadIdx.x & 63) == 0) rsum[threadIdx.x>>6] = s;
    __syncthreads();
    if (threadIdx.x == 0){
        float var = (rsum[0]+rsum[1]+rsum[2]+rsum[3]) * (1.0f/131072.0f); // /(2*H*W)
        sinv = rsqrtf(var + 1e-5f);
    }
    __syncthreads();
    float alpha = (m==0)? 1.f : 2.f;
    float sc = sinv * alpha * (1.0f/256.0f);
    if (km == 0) cr = 0.f;                 // remove mean (DC real part)
    ((float2*)CS)[blockIdx.x*256 + km] = make_float2(cr*sc, ci*sc);
}

// x[b,o,h,w] = gelu( sum_k Re( V_k(w) e^{+i th k h} ) ) + x[b,o,h,w]
__global__ __launch_bounds__(256) void k_synth(const float* __restrict__ CS, float* __restrict__ x){
    int bo = blockIdx.x >> 2, wt = blockIdx.x & 3;
    int lane = threadIdx.x & 63, wv = threadIdx.x >> 6;
    int w = wt*64 + lane;
    const float2* cs = (const float2*)CS + bo*256;
    float Vr[16], Vi[16];
    {
        float stepc, steps; sincosf((float)w*TH_, &steps, &stepc);
        #pragma unroll
        for (int k=0;k<16;++k){ float2 a = cs[k*16]; Vr[k]=a.x; Vi[k]=a.y; }
        float pc = stepc, ps = steps;      // e^{+i m th w}, m=1
        for (int m=1;m<16;++m){
            #pragma unroll
            for (int k=0;k<16;++k){
                float2 a = cs[k*16+m];
                Vr[k] += a.x*pc - a.y*ps;
                Vi[k] += a.x*ps + a.y*pc;
            }
            float nc = pc*stepc - ps*steps;
            ps = pc*steps + ps*stepc;
            pc = nc;
        }
    }
    int h0 = wv*16;
    float rc[16], rs[16], qr[16], qi[16];
    #pragma unroll
    for (int k=0;k<16;++k){
        sincosf((float)k*TH_, &rs[k], &rc[k]);
        float c0, s0; sincosf((float)(k*h0)*TH_, &s0, &c0);
        qr[k] = Vr[k]*c0 - Vi[k]*s0;       // q = V * e^{+i th k h0}
        qi[k] = Vr[k]*s0 + Vi[k]*c0;
    }
    float* xp = x + ((size_t)bo << 16);
    for (int i=0;i<16;++i){
        float y0=0.f,y1=0.f,y2=0.f,y3=0.f;
        #pragma unroll
        for (int k=0;k<16;++k){
            float re = qr[k], im = qi[k];
            y0 += re;                                   // h
            if ((k&3)==0)      { y1 += re; y2 += re; y3 += re; }   // *i^k, *(-1)^k, *(-i)^k
            else if ((k&3)==1) { y1 -= im; y2 -= re; y3 += im; }
            else if ((k&3)==2) { y1 -= re; y2 += re; y3 -= re; }
            else               { y1 += im; y2 -= re; y3 -= im; }
        }
        #pragma unroll
        for (int k=1;k<16;++k){
            float nr = qr[k]*rc[k] - qi[k]*rs[k];
            qi[k]    = qr[k]*rs[k] + qi[k]*rc[k];
            qr[k] = nr;
        }
        int p0 = (h0+i)*256 + w;
        float x0 = xp[p0], x1 = xp[p0+16384], x2 = xp[p0+32768], x3 = xp[p0+49152];
        xp[p0]       = gelu_f(y0) + x0;
        xp[p0+16384] = gelu_f(y1) + x1;
        xp[p0+32768] = gelu_f(y2) + x2;
        xp[p0+49152] = gelu_f(y3) + x3;
    }
}

__global__ __launch_bounds__(256, 4) void k_heads(const float* __restrict__ x,
        const float* __restrict__ fw1, const float* __restrict__ fb1,
        const float* __restrict__ fw2, const float* __restrict__ fb2,
        const float* __restrict__ qw1, const float* __restrict__ qb1,
        const float* __restrict__ qw2, const float* __restrict__ qb2,
        float* __restrict__ J, float* __restrict__ dtP){
    int p = blockIdx.x*256 + threadIdx.x;
    int b = p >> 16, hw = p & (HW-1);
    const float* xp = x + (size_t)b*64*HW + hw;
    float xv[64];
    #pragma unroll
    for (int c=0;c<64;++c) xv[c] = xp[(size_t)c*HW];
    // Force x-vector to stay resident in VGPRs: without this the compiler
    // rematerializes the 64 loads inside the c-loop (64x re-read of x through
    // L1/L2 ~ 8 GiB -> L2-BW-bound, measured 232us with VGPR_Count=44).
    #pragma unroll
    for (int c=0;c<64;++c) asm volatile("" : "+v"(xv[c]));
    float J0=fb2[0], J1=fb2[1], P0=qb2[0], P1=qb2[1];
    #pragma unroll 2
    for (int c=0;c<64;++c){
        float a1 = fb1[c], a2 = qb1[c];
        #pragma unroll
        for (int i=0;i<64;++i){
            a1 = fmaf(fw1[c*64+i], xv[i], a1);
            a2 = fmaf(qw1[c*64+i], xv[i], a2);
        }
        a1 = gelu_f(a1); a2 = gelu_f(a2);
        J0 = fmaf(fw2[c],    a1, J0);
        J1 = fmaf(fw2[64+c], a1, J1);
        P0 = fmaf(qw2[c],    a2, P0);
        P1 = fmaf(qw2[64+c], a2, P1);
    }
    J[(size_t)(b*2+0)*HW + hw] = J0;
    J[(size_t)(b*2+1)*HW + hw] = J1;
    dtP[(size_t)(b*2+0)*HW + hw] = P0;
    dtP[(size_t)(b*2+1)*HW + hw] = P1;
}

// F1[b,f,h,kx] = (1/16) sum_w J[row,w] e^{-i th kx w}
__global__ __launch_bounds__(256) void k_rfftW(const float* __restrict__ J, float* __restrict__ F1x, float* __restrict__ F1y){
    int row = blockIdx.x;             // (b*2+f)*256 + h
    int kx = threadIdx.x;
    if (kx < 129){
        const float* rp = J + (size_t)row*256;
        float sc, ss; sincosf((float)kx*TH_, &ss, &sc);
        float pr=1.f, pi=0.f;          // e^{-i th kx w}
        float ar=0.f, ai=0.f;
        for (int w=0; w<256; ++w){
            float v = rp[w];
            ar = fmaf(v, pr, ar);
            ai = fmaf(v, pi, ai);
            float nr = pr*sc + pi*ss;   // * (sc - i ss)
            pi = pi*sc - pr*ss;
            pr = nr;
        }
        int f = (row >> 8) & 1;
        int bh = ((row >> 9) << 8) | (row & 255);
        float2* outp = (float2*)(f ? F1y : F1x) + (size_t)bh*129 + kx;
        *outp = make_float2(ar*(1.f/16.f), ai*(1.f/16.f));
    }
}

// F2[b,ky,kx] = (1/16)( i*fy(ky)*fftH(F1x) + i*fx(kx)*fftH(F1y) )
__global__ __launch_bounds__(256) void k_fftHdiv(const float* __restrict__ F1x, const float* __restrict__ F1y, float* __restrict__ F2){
    int b = blockIdx.x / 129, kx = blockIdx.x % 129;
    int ky = threadIdx.x;
    const float2* px = (const float2*)F1x + (size_t)b*256*129 + kx;
    const float2* py = (const float2*)F1y + (size_t)b*256*129 + kx;
    float sc, ss; sincosf((float)ky*TH_, &ss, &sc);
    float pr=1.f, pi=0.f;              // e^{-i th ky h}
    float xr=0.f,xi=0.f,yr=0.f,yi=0.f;
    for (int h=0; h<256; ++h){
        float2 vx = px[(size_t)h*129];
        float2 vy = py[(size_t)h*129];
        xr += vx.x*pr - vx.y*pi;  xi += vx.x*pi + vx.y*pr;
        yr += vy.x*pr - vy.y*pi;  yi += vy.x*pi + vy.y*pr;
        float nr = pr*sc + pi*ss; pi = pi*sc - pr*ss; pr = nr;
    }
    float fy = (ky < 128)? (float)ky : (float)(ky-256);
    float fx = (kx < 128)? (float)kx : -128.f;
    float dr = -(fy*xi + fx*yi) * (1.f/16.f);
    float di =  (fy*xr + fx*yr) * (1.f/16.f);
    ((float2*)F2)[(size_t)(b*256+ky)*129 + kx] = make_float2(dr, di);
}

// F3[b,h,kx] = (1/16) sum_ky F2 e^{+i th ky h}
__global__ __launch_bounds__(256) void k_ifftH(const float* __restrict__ F2, float* __restrict__ F3){
    int b = blockIdx.x / 129, kx = blockIdx.x % 129;
    int h = threadIdx.x;
    const float2* p2 = (const float2*)F2 + (size_t)b*256*129 + kx;
    float sc, ss; sincosf((float)h*TH_, &ss, &sc);
    float pr=1.f, pi=0.f;
    float arr=0.f, aii=0.f;
    for (int ky=0; ky<256; ++ky){
        float2 v = p2[(size_t)ky*129];
        arr += v.x*pr - v.y*pi;
        aii += v.x*pi + v.y*pr;
        float nr = pr*sc - pi*ss; pi = pi*sc + pr*ss; pr = nr;  // * (sc + i ss)
    }
    ((float2*)F3)[(size_t)(b*256+h)*129 + kx] = make_float2(arr*(1.f/16.f), aii*(1.f/16.f));
}

// dt_rho = -irfftW(F3); write pred rho (softplus10) and dt rho channels
__global__ __launch_bounds__(256) void k_irfftW(const float* __restrict__ F3, const float* __restrict__ st, float* __restrict__ outp){
    int b = blockIdx.x >> 8, h = blockIdx.x & 255;
    int w = threadIdx.x;
    const float2* rp = (const float2*)F3 + (size_t)(b*256+h)*129;
    float sc, ss; sincosf((float)w*TH_, &ss, &sc);
    float2 b0 = rp[0];
    float y = b0.x;
    float pr = sc, pi = ss;            // kx=1 phase e^{+i th w}
    for (int kx=1; kx<128; ++kx){
        float2 v = rp[kx];
        y += 2.f*(v.x*pr - v.y*pi);
        float nr = pr*sc - pi*ss; pi = pi*sc + pr*ss; pr = nr;
    }
    float2 v128 = rp[128];
    y += (w & 1)? -v128.x : v128.x;
    y *= (1.f/16.f);
    float rho = -y;
    int hw = h*256 + w;
    float s0 = st[(size_t)(b*3)*HW + hw];
    float t = 10.f*fmaf(0.05f, rho, s0);
    float sp = fmaxf(t, 0.f) + log1pf(expf(-fabsf(t)));
    outp[(size_t)(b*3)*HW + hw] = 0.1f*sp;
    outp[(size_t)1572864 + (size_t)(b*3)*HW + hw] = rho;
}

__global__ __launch_bounds__(256) void k_final(const float* __restrict__ dtP, const float* __restrict__ st, float* __restrict__ outp){
    int idx = blockIdx.x*256 + threadIdx.x;   // (b*2+c)*HW + hw
    int b = idx >> 17, r = idx & (2*HW-1);
    int c = r >> 16, hw = r & (HW-1);
    float dp = dtP[idx];
    float sv = st[(size_t)(b*3+1+c)*HW + hw];
    outp[(size_t)(b*3+1+c)*HW + hw] = fmaf(0.05f, dp, sv);
    outp[(size_t)1572864 + (size_t)(b*3+1+c)*HW + hw] = dp;
}

extern "C" void kernel_launch(void* const* d_in, const int* in_sizes, int n_in,
                              void* d_out, int out_size, void* d_ws, size_t ws_size,
                              hipStream_t stream){
    const float* state = (const float*)d_in[0];
    const float* lw  = (const float*)d_in[1];
    const float* lb  = (const float*)d_in[2];
    const float* swr = (const float*)d_in[3];
    const float* swi = (const float*)d_in[4];
    const float* pww = (const float*)d_in[5];
    // d_in[6] = pw_b : cancels exactly in InstanceNorm, unused
    const float* fw1 = (const float*)d_in[7];
    const float* fb1 = (const float*)d_in[8];
    const float* fw2 = (const float*)d_in[9];
    const float* fb2 = (const float*)d_in[10];
    const float* qw1 = (const float*)d_in[11];
    const float* qb1 = (const float*)d_in[12];
    const float* qw2 = (const float*)d_in[13];
    const float* qb2 = (const float*)d_in[14];
    float* outp = (float*)d_out;
    float* ws = (float*)d_ws;

    float* x   = ws;                    // 33,554,432 f32
    float* S   = x   + 33554432;        // 16,384
    float* A   = S   + 16384;           // 262,144
    float* CS  = A   + 262144;          // 262,144
    float* J   = CS  + 262144;          // 1,048,576
    float* dtP = J   + 1048576;         // 1,048,576
    float* F1x = dtP + 1048576;         // 528,384
    float* F1y = F1x + 528384;          // 528,384
    float* F2  = F1y + 528384;          // 528,384
    float* F3  = F2  + 528384;          // 528,384
    float* GH  = F3  + 528384;          // 512

    hipLaunchKernelGGL(k_tables, dim3(1), dim3(256), 0, stream, GH);
    hipLaunchKernelGGL(k_lift, dim3(2048), dim3(256), 0, stream, state, lw, lb, x);
    for (int l=0; l<4; ++l){
        hipLaunchKernelGGL(k_analysis, dim3(512), dim3(256), 0, stream, x, GH, S);
        hipLaunchKernelGGL(k_mixA, dim3(512), dim3(256), 0, stream, S,
                           swr + (size_t)l*1048576, swi + (size_t)l*1048576, A);
        hipLaunchKernelGGL(k_mixB, dim3(512), dim3(256), 0, stream, A, pww + l*4096, CS);
        hipLaunchKernelGGL(k_synth, dim3(2048), dim3(256), 0, stream, CS, x);
    }
    hipLaunchKernelGGL(k_heads, dim3(2048), dim3(256), 0, stream, x,
                       fw1, fb1, fw2, fb2, qw1, qb1, qw2, qb2, J, dtP);
    hipLaunchKernelGGL(k_rfftW,  dim3(4096), dim3(256), 0, stream, J, F1x, F1y);
    hipLaunchKernelGGL(k_fftHdiv, dim3(1032), dim3(256), 0, stream, F1x, F1y, F2);
    hipLaunchKernelGGL(k_ifftH,  dim3(1032), dim3(256), 0, stream, F2, F3);
    hipLaunchKernelGGL(k_irfftW, dim3(2048), dim3(256), 0, stream, F3, state, outp);
    hipLaunchKernelGGL(k_final,  dim3(4096), dim3(256), 0, stream, dtP, state, outp);
}

// Round 3
// 735.538 us; speedup vs baseline: 1.1480x; 1.1404x over previous
//
#include <hip/hip_runtime.h>
#include <math.h>

#define HW 65536
#define TH_ 0.024543692606170259f  // 2*pi/256

typedef __attribute__((ext_vector_type(8))) short bf16x8;
typedef __attribute__((ext_vector_type(4))) float f32x4;

__device__ __forceinline__ float gelu_f(float v){
    return 0.5f*v*(1.0f + erff(v*0.7071067811865476f));
}

__device__ __forceinline__ short f2bf(float f){
    union { float f; unsigned u; } v; v.f = f;
    unsigned r = (v.u + 0x7FFF + ((v.u >> 16) & 1)) >> 16;   // RNE
    return (short)r;
}
__device__ __forceinline__ float bf2f(short s){
    union { float f; unsigned u; } v; v.u = ((unsigned)(unsigned short)s) << 16;
    return v.f;
}

// GH[h] = sum_{ky<16} e^{-2pi i ky h /256}
__global__ void k_tables(float* __restrict__ GH){
    int h = threadIdx.x;
    double gr = 0.0, gi = 0.0;
    for (int ky=0; ky<16; ++ky){
        double a = -2.0*3.14159265358979323846*(double)(ky*h)/256.0;
        gr += cos(a); gi += sin(a);
    }
    GH[2*h] = (float)gr; GH[2*h+1] = (float)gi;
}

// x[b,c,hw] = gelu(sum_i lw[c,i]*state[b,i,hw] + lb[c])
__global__ __launch_bounds__(256) void k_lift(const float* __restrict__ st, const float* __restrict__ lw,
                                              const float* __restrict__ lb, float* __restrict__ x){
    int p = blockIdx.x*256 + threadIdx.x;
    int b = p >> 16, hw = p & (HW-1);
    float s0 = st[(b*3+0)*HW + hw];
    float s1 = st[(b*3+1)*HW + hw];
    float s2 = st[(b*3+2)*HW + hw];
    float* xp = x + (size_t)b*64*HW + hw;
    for (int c=0;c<64;++c){
        float v = fmaf(lw[c*3], s0, fmaf(lw[c*3+1], s1, fmaf(lw[c*3+2], s2, lb[c])));
        xp[(size_t)c*HW] = gelu_f(v);
    }
}

// S[b,i,k] = (1/256) sum_w e^{-i th k w} * (sum_h GH[h]*x[b,i,h,w])
__global__ __launch_bounds__(256) void k_analysis(const float* __restrict__ x, const float* __restrict__ GH,
                                                  float* __restrict__ S){
    int b = blockIdx.x >> 6, i = blockIdx.x & 63;
    int w = threadIdx.x;
    const float* xp = x + ((size_t)(b*64+i))*HW + w;
    float Tr = 0.f, Ti = 0.f;
    #pragma unroll 4
    for (int h=0; h<256; ++h){
        float v = xp[h*256];
        Tr = fmaf(GH[2*h],   v, Tr);
        Ti = fmaf(GH[2*h+1], v, Ti);
    }
    float c1, s1; sincosf((float)w * TH_, &s1, &c1);
    float Sr[16], Si[16];
    float ck = 1.f, sk = 0.f;
    #pragma unroll
    for (int k=0;k<16;++k){
        Sr[k] = Tr*ck + Ti*sk;     // T * e^{-i th k w}
        Si[k] = Ti*ck - Tr*sk;
        float nc = ck*c1 - sk*s1;
        sk = ck*s1 + sk*c1;
        ck = nc;
    }
    #pragma unroll
    for (int k=0;k<16;++k){
        #pragma unroll
        for (int off=32; off; off>>=1){
            Sr[k] += __shfl_xor(Sr[k], off, 64);
            Si[k] += __shfl_xor(Si[k], off, 64);
        }
    }
    __shared__ float red[4][32];
    int wv = threadIdx.x >> 6, ln = threadIdx.x & 63;
    if (ln == 0){
        #pragma unroll
        for (int k=0;k<16;++k){ red[wv][2*k] = Sr[k]; red[wv][2*k+1] = Si[k]; }
    }
    __syncthreads();
    if (threadIdx.x < 32){
        float v = red[0][threadIdx.x]+red[1][threadIdx.x]+red[2][threadIdx.x]+red[3][threadIdx.x];
        S[(b*64+i)*32 + threadIdx.x] = v * (1.0f/256.0f);
    }
}

// A[b,j,km] = sum_i S[b,i,k] * (wr + i wi)[i,j,km]
__global__ __launch_bounds__(256) void k_mixA(const float* __restrict__ S, const float* __restrict__ wr,
                                              const float* __restrict__ wi, float* __restrict__ A){
    int j = blockIdx.x >> 3, b = blockIdx.x & 7;
    __shared__ float sS[2048];
    for (int t=threadIdx.x; t<2048; t+=256) sS[t] = S[b*2048 + t];
    __syncthreads();
    int km = threadIdx.x, k = km >> 4;
    float ar = 0.f, ai = 0.f;
    const float* wrp = wr + j*256 + km;
    const float* wip = wi + j*256 + km;
    #pragma unroll 4
    for (int i=0;i<64;++i){
        float wrv = wrp[i*16384];
        float wiv = wip[i*16384];
        float2 sv = ((const float2*)sS)[i*16 + k];
        ar += sv.x*wrv - sv.y*wiv;
        ai += sv.x*wiv + sv.y*wrv;
    }
    ((float2*)A)[(b*64 + j)*256 + km] = make_float2(ar, ai);
}

// c = sum_j pw[o,j]*A[b,j,km]; Parseval instance-norm stats; CS = c * inv_sigma * alpha(m) / 256
__global__ __launch_bounds__(256) void k_mixB(const float* __restrict__ A, const float* __restrict__ pw,
                                              float* __restrict__ CS){
    int b = blockIdx.x >> 6, o = blockIdx.x & 63;
    int km = threadIdx.x, m = km & 15;
    const float2* Ap = (const float2*)A + b*64*256 + km;
    const float* pwp = pw + o*64;
    float cr=0.f, ci=0.f;
    #pragma unroll 4
    for (int j=0;j<64;++j){
        float p = pwp[j];
        float2 a = Ap[j*256];
        cr = fmaf(p, a.x, cr);
        ci = fmaf(p, a.y, ci);
    }
    float aw = (m==0)? 1.f : 4.f;          // alpha(m)^2
    float s = (km==0)? 0.f : aw*(cr*cr + ci*ci);
    #pragma unroll
    for (int off=32; off; off>>=1) s += __shfl_xor(s, off, 64);
    __shared__ float rsum[4];
    __shared__ float sinv;
    if ((threadIdx.x & 63) == 0) rsum[threadIdx.x>>6] = s;
    __syncthreads();
    if (threadIdx.x == 0){
        float var = (rsum[0]+rsum[1]+rsum[2]+rsum[3]) * (1.0f/131072.0f); // /(2*H*W)
        sinv = rsqrtf(var + 1e-5f);
    }
    __syncthreads();
    float alpha = (m==0)? 1.f : 2.f;
    float sc = sinv * alpha * (1.0f/256.0f);
    if (km == 0) cr = 0.f;                 // remove mean (DC real part)
    ((float2*)CS)[blockIdx.x*256 + km] = make_float2(cr*sc, ci*sc);
}

// x[b,o,h,w] = gelu( sum_k Re( V_k(w) e^{+i th k h} ) ) + x[b,o,h,w]
__global__ __launch_bounds__(256) void k_synth(const float* __restrict__ CS, float* __restrict__ x){
    int bo = blockIdx.x >> 2, wt = blockIdx.x & 3;
    int lane = threadIdx.x & 63, wv = threadIdx.x >> 6;
    int w = wt*64 + lane;
    const float2* cs = (const float2*)CS + bo*256;
    float Vr[16], Vi[16];
    {
        float stepc, steps; sincosf((float)w*TH_, &steps, &stepc);
        #pragma unroll
        for (int k=0;k<16;++k){ float2 a = cs[k*16]; Vr[k]=a.x; Vi[k]=a.y; }
        float pc = stepc, ps = steps;      // e^{+i m th w}, m=1
        for (int m=1;m<16;++m){
            #pragma unroll
            for (int k=0;k<16;++k){
                float2 a = cs[k*16+m];
                Vr[k] += a.x*pc - a.y*ps;
                Vi[k] += a.x*ps + a.y*pc;
            }
            float nc = pc*stepc - ps*steps;
            ps = pc*steps + ps*stepc;
            pc = nc;
        }
    }
    int h0 = wv*16;
    float rc[16], rs[16], qr[16], qi[16];
    #pragma unroll
    for (int k=0;k<16;++k){
        sincosf((float)k*TH_, &rs[k], &rc[k]);
        float c0, s0; sincosf((float)(k*h0)*TH_, &s0, &c0);
        qr[k] = Vr[k]*c0 - Vi[k]*s0;       // q = V * e^{+i th k h0}
        qi[k] = Vr[k]*s0 + Vi[k]*c0;
    }
    float* xp = x + ((size_t)bo << 16);
    for (int i=0;i<16;++i){
        float y0=0.f,y1=0.f,y2=0.f,y3=0.f;
        #pragma unroll
        for (int k=0;k<16;++k){
            float re = qr[k], im = qi[k];
            y0 += re;                                   // h
            if ((k&3)==0)      { y1 += re; y2 += re; y3 += re; }   // *i^k, *(-1)^k, *(-i)^k
            else if ((k&3)==1) { y1 -= im; y2 -= re; y3 += im; }
            else if ((k&3)==2) { y1 -= re; y2 += re; y3 -= re; }
            else               { y1 += im; y2 -= re; y3 -= im; }
        }
        #pragma unroll
        for (int k=1;k<16;++k){
            float nr = qr[k]*rc[k] - qi[k]*rs[k];
            qi[k]    = qr[k]*rs[k] + qi[k]*rc[k];
            qr[k] = nr;
        }
        int p0 = (h0+i)*256 + w;
        float x0 = xp[p0], x1 = xp[p0+16384], x2 = xp[p0+32768], x3 = xp[p0+49152];
        xp[p0]       = gelu_f(y0) + x0;
        xp[p0+16384] = gelu_f(y1) + x1;
        xp[p0+32768] = gelu_f(y2) + x2;
        xp[p0+49152] = gelu_f(y3) + x3;
    }
}

// MFMA heads: per wave 64 px; A-frags (x, split hi/lo bf16) resident in VGPRs.
// D = Ahi*Bhi + Ahi*Blo + Alo*Bhi  (split-bf16, rel err ~3e-5)
// layer2 (128->4) fused in D-layout (col=lane&15=out ch, row=(lane>>4)*4+r=px),
// reduced over the 16 out-ch lanes via shfl_xor.
__global__ __launch_bounds__(256) void k_heads(const float* __restrict__ x,
        const float* __restrict__ fw1, const float* __restrict__ fb1,
        const float* __restrict__ fw2, const float* __restrict__ fb2,
        const float* __restrict__ qw1, const float* __restrict__ qb1,
        const float* __restrict__ qw2, const float* __restrict__ qb2,
        float* __restrict__ J, float* __restrict__ dtP){
    int wv = threadIdx.x >> 6, lane = threadIdx.x & 63;
    int l15 = lane & 15, lg = lane >> 4;
    int px0 = blockIdx.x*256 + wv*64;
    int b = px0 >> 16;
    int hwbase = px0 & (HW-1);
    const float* xb = x + (size_t)b*64*HW;

    // ---- A fragments: 4 M-tiles x 2 k-steps, hi/lo bf16
    bf16x8 Ahi[4][2], Alo[4][2];
    #pragma unroll
    for (int mt=0; mt<4; ++mt){
        int px = hwbase + mt*16 + l15;
        #pragma unroll
        for (int ks=0; ks<2; ++ks){
            #pragma unroll
            for (int j=0; j<8; ++j){
                int ch = ks*32 + lg*8 + j;
                float f = xb[(size_t)ch*HW + px];
                short hi = f2bf(f);
                Ahi[mt][ks][j] = hi;
                Alo[mt][ks][j] = f2bf(f - bf2f(hi));
            }
        }
    }

    #pragma unroll
    for (int ph=0; ph<2; ++ph){
        const float* w1p = ph ? qw1 : fw1;
        const float* b1p = ph ? qb1 : fb1;
        const float* w2p = ph ? qw2 : fw2;
        const float* b2p = ph ? qb2 : fb2;
        float* outp = ph ? dtP : J;

        float p0[16], p1[16];
        #pragma unroll
        for (int t=0;t<16;++t){ p0[t]=0.f; p1[t]=0.f; }

        for (int n=0; n<4; ++n){
            int oc = n*16 + l15;
            bf16x8 Bhi[2], Blo[2];
            #pragma unroll
            for (int ks=0; ks<2; ++ks){
                const float* wp = w1p + oc*64 + ks*32 + lg*8;
                #pragma unroll
                for (int j=0;j<8;++j){
                    float f = wp[j];
                    short hi = f2bf(f);
                    Bhi[ks][j] = hi;
                    Blo[ks][j] = f2bf(f - bf2f(hi));
                }
            }
            float bias = b1p[oc];
            float w2a = w2p[oc], w2b = w2p[64+oc];
            #pragma unroll
            for (int mt=0; mt<4; ++mt){
                f32x4 d = {0.f,0.f,0.f,0.f};
                #pragma unroll
                for (int ks=0; ks<2; ++ks){
                    d = __builtin_amdgcn_mfma_f32_16x16x32_bf16(Ahi[mt][ks], Bhi[ks], d, 0,0,0);
                    d = __builtin_amdgcn_mfma_f32_16x16x32_bf16(Ahi[mt][ks], Blo[ks], d, 0,0,0);
                    d = __builtin_amdgcn_mfma_f32_16x16x32_bf16(Alo[mt][ks], Bhi[ks], d, 0,0,0);
                }
                #pragma unroll
                for (int r=0;r<4;++r){
                    float g = gelu_f(d[r] + bias);
                    p0[mt*4+r] = fmaf(w2a, g, p0[mt*4+r]);
                    p1[mt*4+r] = fmaf(w2b, g, p1[mt*4+r]);
                }
            }
        }
        #pragma unroll
        for (int t=0;t<16;++t){
            #pragma unroll
            for (int off=1; off<16; off<<=1){
                p0[t] += __shfl_xor(p0[t], off, 64);
                p1[t] += __shfl_xor(p1[t], off, 64);
            }
        }
        float bo0 = b2p[0], bo1 = b2p[1];
        if (l15 == 0){
            float* plane = outp + ((size_t)(b*2 + 0))*HW;
            #pragma unroll
            for (int mt=0; mt<4; ++mt){
                int px = hwbase + mt*16 + lg*4;
                float4 v; v.x=p0[mt*4+0]+bo0; v.y=p0[mt*4+1]+bo0; v.z=p0[mt*4+2]+bo0; v.w=p0[mt*4+3]+bo0;
                *(float4*)(plane + px) = v;
            }
        } else if (l15 == 1){
            float* plane = outp + ((size_t)(b*2 + 1))*HW;
            #pragma unroll
            for (int mt=0; mt<4; ++mt){
                int px = hwbase + mt*16 + lg*4;
                float4 v; v.x=p1[mt*4+0]+bo1; v.y=p1[mt*4+1]+bo1; v.z=p1[mt*4+2]+bo1; v.w=p1[mt*4+3]+bo1;
                *(float4*)(plane + px) = v;
            }
        }
    }
}

// F1[b,f,h,kx] = (1/16) sum_w J[row,w] e^{-i th kx w}
__global__ __launch_bounds__(256) void k_rfftW(const float* __restrict__ J, float* __restrict__ F1x, float* __restrict__ F1y){
    int row = blockIdx.x;             // (b*2+f)*256 + h
    int kx = threadIdx.x;
    if (kx < 129){
        const float* rp = J + (size_t)row*256;
        float sc, ss; sincosf((float)kx*TH_, &ss, &sc);
        float pr=1.f, pi=0.f;          // e^{-i th kx w}
        float ar=0.f, ai=0.f;
        for (int w=0; w<256; ++w){
            float v = rp[w];
            ar = fmaf(v, pr, ar);
            ai = fmaf(v, pi, ai);
            float nr = pr*sc + pi*ss;   // * (sc - i ss)
            pi = pi*sc - pr*ss;
            pr = nr;
        }
        int f = (row >> 8) & 1;
        int bh = ((row >> 9) << 8) | (row & 255);
        float2* outp = (float2*)(f ? F1y : F1x) + (size_t)bh*129 + kx;
        *outp = make_float2(ar*(1.f/16.f), ai*(1.f/16.f));
    }
}

// F2[b,ky,kx] = (1/16)( i*fy(ky)*fftH(F1x) + i*fx(kx)*fftH(F1y) )
__global__ __launch_bounds__(256) void k_fftHdiv(const float* __restrict__ F1x, const float* __restrict__ F1y, float* __restrict__ F2){
    int b = blockIdx.x / 129, kx = blockIdx.x % 129;
    int ky = threadIdx.x;
    const float2* px = (const float2*)F1x + (size_t)b*256*129 + kx;
    const float2* py = (const float2*)F1y + (size_t)b*256*129 + kx;
    float sc, ss; sincosf((float)ky*TH_, &ss, &sc);
    float pr=1.f, pi=0.f;              // e^{-i th ky h}
    float xr=0.f,xi=0.f,yr=0.f,yi=0.f;
    for (int h=0; h<256; ++h){
        float2 vx = px[(size_t)h*129];
        float2 vy = py[(size_t)h*129];
        xr += vx.x*pr - vx.y*pi;  xi += vx.x*pi + vx.y*pr;
        yr += vy.x*pr - vy.y*pi;  yi += vy.x*pi + vy.y*pr;
        float nr = pr*sc + pi*ss; pi = pi*sc - pr*ss; pr = nr;
    }
    float fy = (ky < 128)? (float)ky : (float)(ky-256);
    float fx = (kx < 128)? (float)kx : -128.f;
    float dr = -(fy*xi + fx*yi) * (1.f/16.f);
    float di =  (fy*xr + fx*yr) * (1.f/16.f);
    ((float2*)F2)[(size_t)(b*256+ky)*129 + kx] = make_float2(dr, di);
}

// F3[b,h,kx] = (1/16) sum_ky F2 e^{+i th ky h}
__global__ __launch_bounds__(256) void k_ifftH(const float* __restrict__ F2, float* __restrict__ F3){
    int b = blockIdx.x / 129, kx = blockIdx.x % 129;
    int h = threadIdx.x;
    const float2* p2 = (const float2*)F2 + (size_t)b*256*129 + kx;
    float sc, ss; sincosf((float)h*TH_, &ss, &sc);
    float pr=1.f, pi=0.f;
    float arr=0.f, aii=0.f;
    for (int ky=0; ky<256; ++ky){
        float2 v = p2[(size_t)ky*129];
        arr += v.x*pr - v.y*pi;
        aii += v.x*pi + v.y*pr;
        float nr = pr*sc - pi*ss; pi = pi*sc + pr*ss; pr = nr;  // * (sc + i ss)
    }
    ((float2*)F3)[(size_t)(b*256+h)*129 + kx] = make_float2(arr*(1.f/16.f), aii*(1.f/16.f));
}

// dt_rho = -irfftW(F3); write pred rho (softplus10) and dt rho channels
__global__ __launch_bounds__(256) void k_irfftW(const float* __restrict__ F3, const float* __restrict__ st, float* __restrict__ outp){
    int b = blockIdx.x >> 8, h = blockIdx.x & 255;
    int w = threadIdx.x;
    const float2* rp = (const float2*)F3 + (size_t)(b*256+h)*129;
    float sc, ss; sincosf((float)w*TH_, &ss, &sc);
    float2 b0 = rp[0];
    float y = b0.x;
    float pr = sc, pi = ss;            // kx=1 phase e^{+i th w}
    for (int kx=1; kx<128; ++kx){
        float2 v = rp[kx];
        y += 2.f*(v.x*pr - v.y*pi);
        float nr = pr*sc - pi*ss; pi = pi*sc + pr*ss; pr = nr;
    }
    float2 v128 = rp[128];
    y += (w & 1)? -v128.x : v128.x;
    y *= (1.f/16.f);
    float rho = -y;
    int hw = h*256 + w;
    float s0 = st[(size_t)(b*3)*HW + hw];
    float t = 10.f*fmaf(0.05f, rho, s0);
    float sp = fmaxf(t, 0.f) + log1pf(expf(-fabsf(t)));
    outp[(size_t)(b*3)*HW + hw] = 0.1f*sp;
    outp[(size_t)1572864 + (size_t)(b*3)*HW + hw] = rho;
}

__global__ __launch_bounds__(256) void k_final(const float* __restrict__ dtP, const float* __restrict__ st, float* __restrict__ outp){
    int idx = blockIdx.x*256 + threadIdx.x;   // (b*2+c)*HW + hw
    int b = idx >> 17, r = idx & (2*HW-1);
    int c = r >> 16, hw = r & (HW-1);
    float dp = dtP[idx];
    float sv = st[(size_t)(b*3+1+c)*HW + hw];
    outp[(size_t)(b*3+1+c)*HW + hw] = fmaf(0.05f, dp, sv);
    outp[(size_t)1572864 + (size_t)(b*3+1+c)*HW + hw] = dp;
}

extern "C" void kernel_launch(void* const* d_in, const int* in_sizes, int n_in,
                              void* d_out, int out_size, void* d_ws, size_t ws_size,
                              hipStream_t stream){
    const float* state = (const float*)d_in[0];
    const float* lw  = (const float*)d_in[1];
    const float* lb  = (const float*)d_in[2];
    const float* swr = (const float*)d_in[3];
    const float* swi = (const float*)d_in[4];
    const float* pww = (const float*)d_in[5];
    // d_in[6] = pw_b : cancels exactly in InstanceNorm, unused
    const float* fw1 = (const float*)d_in[7];
    const float* fb1 = (const float*)d_in[8];
    const float* fw2 = (const float*)d_in[9];
    const float* fb2 = (const float*)d_in[10];
    const float* qw1 = (const float*)d_in[11];
    const float* qb1 = (const float*)d_in[12];
    const float* qw2 = (const float*)d_in[13];
    const float* qb2 = (const float*)d_in[14];
    float* outp = (float*)d_out;
    float* ws = (float*)d_ws;

    float* x   = ws;                    // 33,554,432 f32
    float* S   = x   + 33554432;        // 16,384
    float* A   = S   + 16384;           // 262,144
    float* CS  = A   + 262144;          // 262,144
    float* J   = CS  + 262144;          // 1,048,576
    float* dtP = J   + 1048576;         // 1,048,576
    float* F1x = dtP + 1048576;         // 528,384
    float* F1y = F1x + 528384;          // 528,384
    float* F2  = F1y + 528384;          // 528,384
    float* F3  = F2  + 528384;          // 528,384
    float* GH  = F3  + 528384;          // 512

    hipLaunchKernelGGL(k_tables, dim3(1), dim3(256), 0, stream, GH);
    hipLaunchKernelGGL(k_lift, dim3(2048), dim3(256), 0, stream, state, lw, lb, x);
    for (int l=0; l<4; ++l){
        hipLaunchKernelGGL(k_analysis, dim3(512), dim3(256), 0, stream, x, GH, S);
        hipLaunchKernelGGL(k_mixA, dim3(512), dim3(256), 0, stream, S,
                           swr + (size_t)l*1048576, swi + (size_t)l*1048576, A);
        hipLaunchKernelGGL(k_mixB, dim3(512), dim3(256), 0, stream, A, pww + l*4096, CS);
        hipLaunchKernelGGL(k_synth, dim3(2048), dim3(256), 0, stream, CS, x);
    }
    hipLaunchKernelGGL(k_heads, dim3(2048), dim3(256), 0, stream, x,
                       fw1, fb1, fw2, fb2, qw1, qb1, qw2, qb2, J, dtP);
    hipLaunchKernelGGL(k_rfftW,  dim3(4096), dim3(256), 0, stream, J, F1x, F1y);
    hipLaunchKernelGGL(k_fftHdiv, dim3(1032), dim3(256), 0, stream, F1x, F1y, F2);
    hipLaunchKernelGGL(k_ifftH,  dim3(1032), dim3(256), 0, stream, F2, F3);
    hipLaunchKernelGGL(k_irfftW, dim3(2048), dim3(256), 0, stream, F3, state, outp);
    hipLaunchKernelGGL(k_final,  dim3(4096), dim3(256), 0, stream, dtP, state, outp);
}

// Round 4
// 664.579 us; speedup vs baseline: 1.2706x; 1.1068x over previous
//
#include <hip/hip_runtime.h>
#include <math.h>

#define HW 65536
#define TH_ 0.024543692606170259f  // 2*pi/256

typedef __attribute__((ext_vector_type(8))) short bf16x8;
typedef __attribute__((ext_vector_type(4))) float f32x4;

// Fast gelu: Abramowitz-Stegun 7.1.26 erf, |abs err| <= ~3e-7 (vs libm erff ~45 instrs).
// Error budget: gelu abs err ~1e-6, 4 orders below the passing bf16-split noise.
__device__ __forceinline__ float gelu_f(float v){
    float u = fabsf(v)*0.7071067811865476f;
    float t = __builtin_amdgcn_rcpf(fmaf(0.3275911f, u, 1.0f));
    float p = t*fmaf(t, fmaf(t, fmaf(t, fmaf(t, 1.061405429f, -1.453152027f),
                     1.421413741f), -0.284496736f), 0.254829592f);
    float e = __expf(-u*u);
    float erfu = fmaf(-p, e, 1.0f);          // erf(|v|/sqrt2)
    float er = copysignf(erfu, v);
    return 0.5f*v*(1.0f+er);
}

__device__ __forceinline__ short f2bf(float f){
    union { float f; unsigned u; } v; v.f = f;
    unsigned r = (v.u + 0x7FFF + ((v.u >> 16) & 1)) >> 16;   // RNE
    return (short)r;
}
__device__ __forceinline__ float bf2f(short s){
    union { float f; unsigned u; } v; v.u = ((unsigned)(unsigned short)s) << 16;
    return v.f;
}

// GH[h] = sum_{ky<16} e^{-2pi i ky h /256}
__global__ void k_tables(float* __restrict__ GH){
    int h = threadIdx.x;
    double gr = 0.0, gi = 0.0;
    for (int ky=0; ky<16; ++ky){
        double a = -2.0*3.14159265358979323846*(double)(ky*h)/256.0;
        gr += cos(a); gi += sin(a);
    }
    GH[2*h] = (float)gr; GH[2*h+1] = (float)gi;
}

// x[b,c,hw] = gelu(sum_i lw[c,i]*state[b,i,hw] + lb[c])
__global__ __launch_bounds__(256) void k_lift(const float* __restrict__ st, const float* __restrict__ lw,
                                              const float* __restrict__ lb, float* __restrict__ x){
    int p = blockIdx.x*256 + threadIdx.x;
    int b = p >> 16, hw = p & (HW-1);
    float s0 = st[(b*3+0)*HW + hw];
    float s1 = st[(b*3+1)*HW + hw];
    float s2 = st[(b*3+2)*HW + hw];
    float* xp = x + (size_t)b*64*HW + hw;
    for (int c=0;c<64;++c){
        float v = fmaf(lw[c*3], s0, fmaf(lw[c*3+1], s1, fmaf(lw[c*3+2], s2, lb[c])));
        xp[(size_t)c*HW] = gelu_f(v);
    }
}

// Layer-0 analysis (reads x): S[b,i,k] = (1/256) sum_w e^{-i th k w} * (sum_h GH[h]*x[b,i,h,w])
__global__ __launch_bounds__(256) void k_analysis(const float* __restrict__ x, const float* __restrict__ GH,
                                                  float* __restrict__ S){
    int b = blockIdx.x >> 6, i = blockIdx.x & 63;
    int w = threadIdx.x;
    const float* xp = x + ((size_t)(b*64+i))*HW + w;
    float Tr = 0.f, Ti = 0.f;
    #pragma unroll 4
    for (int h=0; h<256; ++h){
        float v = xp[h*256];
        Tr = fmaf(GH[2*h],   v, Tr);
        Ti = fmaf(GH[2*h+1], v, Ti);
    }
    float c1, s1; sincosf((float)w * TH_, &s1, &c1);
    float Sr[16], Si[16];
    float ck = 1.f, sk = 0.f;
    #pragma unroll
    for (int k=0;k<16;++k){
        Sr[k] = Tr*ck + Ti*sk;     // T * e^{-i th k w}
        Si[k] = Ti*ck - Tr*sk;
        float nc = ck*c1 - sk*s1;
        sk = ck*s1 + sk*c1;
        ck = nc;
    }
    #pragma unroll
    for (int k=0;k<16;++k){
        #pragma unroll
        for (int off=32; off; off>>=1){
            Sr[k] += __shfl_xor(Sr[k], off, 64);
            Si[k] += __shfl_xor(Si[k], off, 64);
        }
    }
    __shared__ float red[4][32];
    int wv = threadIdx.x >> 6, ln = threadIdx.x & 63;
    if (ln == 0){
        #pragma unroll
        for (int k=0;k<16;++k){ red[wv][2*k] = Sr[k]; red[wv][2*k+1] = Si[k]; }
    }
    __syncthreads();
    if (threadIdx.x < 32){
        float v = red[0][threadIdx.x]+red[1][threadIdx.x]+red[2][threadIdx.x]+red[3][threadIdx.x];
        S[(b*64+i)*32 + threadIdx.x] = v * (1.0f/256.0f);
    }
}

// Layers 1-3: analysis from fused T[b,i,w] (1 MB) instead of re-reading x (134 MB)
__global__ __launch_bounds__(256) void k_analysisT(const float* __restrict__ T, float* __restrict__ S){
    int bi = blockIdx.x;               // b*64+i
    int w = threadIdx.x;
    float2 t = ((const float2*)T)[bi*256 + w];
    float Tr = t.x, Ti = t.y;
    float c1, s1; sincosf((float)w * TH_, &s1, &c1);
    float Sr[16], Si[16];
    float ck = 1.f, sk = 0.f;
    #pragma unroll
    for (int k=0;k<16;++k){
        Sr[k] = Tr*ck + Ti*sk;
        Si[k] = Ti*ck - Tr*sk;
        float nc = ck*c1 - sk*s1;
        sk = ck*s1 + sk*c1;
        ck = nc;
    }
    #pragma unroll
    for (int k=0;k<16;++k){
        #pragma unroll
        for (int off=32; off; off>>=1){
            Sr[k] += __shfl_xor(Sr[k], off, 64);
            Si[k] += __shfl_xor(Si[k], off, 64);
        }
    }
    __shared__ float red[4][32];
    int wv = threadIdx.x >> 6, ln = threadIdx.x & 63;
    if (ln == 0){
        #pragma unroll
        for (int k=0;k<16;++k){ red[wv][2*k] = Sr[k]; red[wv][2*k+1] = Si[k]; }
    }
    __syncthreads();
    if (threadIdx.x < 32){
        float v = red[0][threadIdx.x]+red[1][threadIdx.x]+red[2][threadIdx.x]+red[3][threadIdx.x];
        S[bi*32 + threadIdx.x] = v * (1.0f/256.0f);
    }
}

// A[b,j,km] = sum_i S[b,i,k] * (wr + i wi)[i,j,km]
__global__ __launch_bounds__(256) void k_mixA(const float* __restrict__ S, const float* __restrict__ wr,
                                              const float* __restrict__ wi, float* __restrict__ A){
    int j = blockIdx.x >> 3, b = blockIdx.x & 7;
    __shared__ float sS[2048];
    for (int t=threadIdx.x; t<2048; t+=256) sS[t] = S[b*2048 + t];
    __syncthreads();
    int km = threadIdx.x, k = km >> 4;
    float ar = 0.f, ai = 0.f;
    const float* wrp = wr + j*256 + km;
    const float* wip = wi + j*256 + km;
    #pragma unroll 4
    for (int i=0;i<64;++i){
        float wrv = wrp[i*16384];
        float wiv = wip[i*16384];
        float2 sv = ((const float2*)sS)[i*16 + k];
        ar += sv.x*wrv - sv.y*wiv;
        ai += sv.x*wiv + sv.y*wrv;
    }
    ((float2*)A)[(b*64 + j)*256 + km] = make_float2(ar, ai);
}

// c = sum_j pw[o,j]*A[b,j,km]; Parseval instance-norm stats; CS = c * inv_sigma * alpha(m) / 256
__global__ __launch_bounds__(256) void k_mixB(const float* __restrict__ A, const float* __restrict__ pw,
                                              float* __restrict__ CS){
    int b = blockIdx.x >> 6, o = blockIdx.x & 63;
    int km = threadIdx.x, m = km & 15;
    const float2* Ap = (const float2*)A + b*64*256 + km;
    const float* pwp = pw + o*64;
    float cr=0.f, ci=0.f;
    #pragma unroll 4
    for (int j=0;j<64;++j){
        float p = pwp[j];
        float2 a = Ap[j*256];
        cr = fmaf(p, a.x, cr);
        ci = fmaf(p, a.y, ci);
    }
    float aw = (m==0)? 1.f : 4.f;          // alpha(m)^2
    float s = (km==0)? 0.f : aw*(cr*cr + ci*ci);
    #pragma unroll
    for (int off=32; off; off>>=1) s += __shfl_xor(s, off, 64);
    __shared__ float rsum[4];
    __shared__ float sinv;
    if ((threadIdx.x & 63) == 0) rsum[threadIdx.x>>6] = s;
    __syncthreads();
    if (threadIdx.x == 0){
        float var = (rsum[0]+rsum[1]+rsum[2]+rsum[3]) * (1.0f/131072.0f); // /(2*H*W)
        sinv = rsqrtf(var + 1e-5f);
    }
    __syncthreads();
    float alpha = (m==0)? 1.f : 2.f;
    float sc = sinv * alpha * (1.0f/256.0f);
    if (km == 0) cr = 0.f;                 // remove mean (DC real part)
    ((float2*)CS)[blockIdx.x*256 + km] = make_float2(cr*sc, ci*sc);
}

// x[b,o,h,w] = gelu( sum_k Re( V_k(w) e^{+i th k h} ) ) + x[b,o,h,w]
// EMIT_T: also accumulate T[b,o,w] = sum_h GH[h]*x_new[h,w] for the next layer's analysis.
template<bool EMIT_T>
__global__ __launch_bounds__(256) void k_synth(const float* __restrict__ CS, float* __restrict__ x,
                                               const float* __restrict__ GH, float* __restrict__ T){
    int bo = blockIdx.x >> 2, wt = blockIdx.x & 3;
    int lane = threadIdx.x & 63, wv = threadIdx.x >> 6;
    int w = wt*64 + lane;
    __shared__ float sGH[512];
    if (EMIT_T){
        sGH[threadIdx.x] = GH[threadIdx.x];
        sGH[256+threadIdx.x] = GH[256+threadIdx.x];
        __syncthreads();
    }
    const float2* cs = (const float2*)CS + bo*256;
    float Vr[16], Vi[16];
    {
        float stepc, steps; sincosf((float)w*TH_, &steps, &stepc);
        #pragma unroll
        for (int k=0;k<16;++k){ float2 a = cs[k*16]; Vr[k]=a.x; Vi[k]=a.y; }
        float pc = stepc, ps = steps;      // e^{+i m th w}, m=1
        for (int m=1;m<16;++m){
            #pragma unroll
            for (int k=0;k<16;++k){
                float2 a = cs[k*16+m];
                Vr[k] += a.x*pc - a.y*ps;
                Vi[k] += a.x*ps + a.y*pc;
            }
            float nc = pc*stepc - ps*steps;
            ps = pc*steps + ps*stepc;
            pc = nc;
        }
    }
    int h0 = wv*16;
    float rc[16], rs[16], qr[16], qi[16];
    #pragma unroll
    for (int k=0;k<16;++k){
        sincosf((float)k*TH_, &rs[k], &rc[k]);
        float c0, s0; sincosf((float)(k*h0)*TH_, &s0, &c0);
        qr[k] = Vr[k]*c0 - Vi[k]*s0;       // q = V * e^{+i th k h0}
        qi[k] = Vr[k]*s0 + Vi[k]*c0;
    }
    float* xp = x + ((size_t)bo << 16);
    float Tr = 0.f, Ti = 0.f;
    for (int i=0;i<16;++i){
        float y0=0.f,y1=0.f,y2=0.f,y3=0.f;
        #pragma unroll
        for (int k=0;k<16;++k){
            float re = qr[k], im = qi[k];
            y0 += re;                                   // h
            if ((k&3)==0)      { y1 += re; y2 += re; y3 += re; }   // *i^k, *(-1)^k, *(-i)^k
            else if ((k&3)==1) { y1 -= im; y2 -= re; y3 += im; }
            else if ((k&3)==2) { y1 -= re; y2 += re; y3 -= re; }
            else               { y1 += im; y2 -= re; y3 -= im; }
        }
        #pragma unroll
        for (int k=1;k<16;++k){
            float nr = qr[k]*rc[k] - qi[k]*rs[k];
            qi[k]    = qr[k]*rs[k] + qi[k]*rc[k];
            qr[k] = nr;
        }
        int p0 = (h0+i)*256 + w;
        float x0 = xp[p0], x1 = xp[p0+16384], x2 = xp[p0+32768], x3 = xp[p0+49152];
        float n0 = gelu_f(y0) + x0;
        float n1 = gelu_f(y1) + x1;
        float n2 = gelu_f(y2) + x2;
        float n3 = gelu_f(y3) + x3;
        xp[p0]       = n0;
        xp[p0+16384] = n1;
        xp[p0+32768] = n2;
        xp[p0+49152] = n3;
        if (EMIT_T){
            int h = h0+i;
            Tr = fmaf(sGH[2*h],     n0, Tr);  Ti = fmaf(sGH[2*h+1],     n0, Ti);
            Tr = fmaf(sGH[2*h+128], n1, Tr);  Ti = fmaf(sGH[2*h+129],   n1, Ti);
            Tr = fmaf(sGH[2*h+256], n2, Tr);  Ti = fmaf(sGH[2*h+257],   n2, Ti);
            Tr = fmaf(sGH[2*h+384], n3, Tr);  Ti = fmaf(sGH[2*h+385],   n3, Ti);
        }
    }
    if (EMIT_T){
        __shared__ float2 tpart[4][64];
        tpart[wv][lane] = make_float2(Tr, Ti);
        __syncthreads();
        if (wv == 0){
            float2 a = tpart[0][lane], b2 = tpart[1][lane];
            float2 c = tpart[2][lane], d = tpart[3][lane];
            ((float2*)T)[bo*256 + w] = make_float2(a.x+b2.x+c.x+d.x, a.y+b2.y+c.y+d.y);
        }
    }
}

// MFMA heads: per wave 64 px; A-frags (x, split hi/lo bf16) resident in VGPRs.
// D = Ahi*Bhi + Ahi*Blo + Alo*Bhi  (split-bf16, rel err ~3e-5)
// layer2 (128->4) fused in D-layout (col=lane&15=out ch, row=(lane>>4)*4+r=px),
// reduced over the 16 out-ch lanes via shfl_xor.
__global__ __launch_bounds__(256) void k_heads(const float* __restrict__ x,
        const float* __restrict__ fw1, const float* __restrict__ fb1,
        const float* __restrict__ fw2, const float* __restrict__ fb2,
        const float* __restrict__ qw1, const float* __restrict__ qb1,
        const float* __restrict__ qw2, const float* __restrict__ qb2,
        float* __restrict__ J, float* __restrict__ dtP){
    int wv = threadIdx.x >> 6, lane = threadIdx.x & 63;
    int l15 = lane & 15, lg = lane >> 4;
    int px0 = blockIdx.x*256 + wv*64;
    int b = px0 >> 16;
    int hwbase = px0 & (HW-1);
    const float* xb = x + (size_t)b*64*HW;

    // ---- A fragments: 4 M-tiles x 2 k-steps, hi/lo bf16
    bf16x8 Ahi[4][2], Alo[4][2];
    #pragma unroll
    for (int mt=0; mt<4; ++mt){
        int px = hwbase + mt*16 + l15;
        #pragma unroll
        for (int ks=0; ks<2; ++ks){
            #pragma unroll
            for (int j=0; j<8; ++j){
                int ch = ks*32 + lg*8 + j;
                float f = xb[(size_t)ch*HW + px];
                short hi = f2bf(f);
                Ahi[mt][ks][j] = hi;
                Alo[mt][ks][j] = f2bf(f - bf2f(hi));
            }
        }
    }

    #pragma unroll
    for (int ph=0; ph<2; ++ph){
        const float* w1p = ph ? qw1 : fw1;
        const float* b1p = ph ? qb1 : fb1;
        const float* w2p = ph ? qw2 : fw2;
        const float* b2p = ph ? qb2 : fb2;
        float* outp = ph ? dtP : J;

        float p0[16], p1[16];
        #pragma unroll
        for (int t=0;t<16;++t){ p0[t]=0.f; p1[t]=0.f; }

        for (int n=0; n<4; ++n){
            int oc = n*16 + l15;
            bf16x8 Bhi[2], Blo[2];
            #pragma unroll
            for (int ks=0; ks<2; ++ks){
                const float* wp = w1p + oc*64 + ks*32 + lg*8;
                #pragma unroll
                for (int j=0;j<8;++j){
                    float f = wp[j];
                    short hi = f2bf(f);
                    Bhi[ks][j] = hi;
                    Blo[ks][j] = f2bf(f - bf2f(hi));
                }
            }
            float bias = b1p[oc];
            float w2a = w2p[oc], w2b = w2p[64+oc];
            #pragma unroll
            for (int mt=0; mt<4; ++mt){
                f32x4 d = {0.f,0.f,0.f,0.f};
                #pragma unroll
                for (int ks=0; ks<2; ++ks){
                    d = __builtin_amdgcn_mfma_f32_16x16x32_bf16(Ahi[mt][ks], Bhi[ks], d, 0,0,0);
                    d = __builtin_amdgcn_mfma_f32_16x16x32_bf16(Ahi[mt][ks], Blo[ks], d, 0,0,0);
                    d = __builtin_amdgcn_mfma_f32_16x16x32_bf16(Alo[mt][ks], Bhi[ks], d, 0,0,0);
                }
                #pragma unroll
                for (int r=0;r<4;++r){
                    float g = gelu_f(d[r] + bias);
                    p0[mt*4+r] = fmaf(w2a, g, p0[mt*4+r]);
                    p1[mt*4+r] = fmaf(w2b, g, p1[mt*4+r]);
                }
            }
        }
        #pragma unroll
        for (int t=0;t<16;++t){
            #pragma unroll
            for (int off=1; off<16; off<<=1){
                p0[t] += __shfl_xor(p0[t], off, 64);
                p1[t] += __shfl_xor(p1[t], off, 64);
            }
        }
        float bo0 = b2p[0], bo1 = b2p[1];
        if (l15 == 0){
            float* plane = outp + ((size_t)(b*2 + 0))*HW;
            #pragma unroll
            for (int mt=0; mt<4; ++mt){
                int px = hwbase + mt*16 + lg*4;
                float4 v; v.x=p0[mt*4+0]+bo0; v.y=p0[mt*4+1]+bo0; v.z=p0[mt*4+2]+bo0; v.w=p0[mt*4+3]+bo0;
                *(float4*)(plane + px) = v;
            }
        } else if (l15 == 1){
            float* plane = outp + ((size_t)(b*2 + 1))*HW;
            #pragma unroll
            for (int mt=0; mt<4; ++mt){
                int px = hwbase + mt*16 + lg*4;
                float4 v; v.x=p1[mt*4+0]+bo1; v.y=p1[mt*4+1]+bo1; v.z=p1[mt*4+2]+bo1; v.w=p1[mt*4+3]+bo1;
                *(float4*)(plane + px) = v;
            }
        }
    }
}

// F1[b,f,h,kx] = (1/16) sum_w J[row,w] e^{-i th kx w}
__global__ __launch_bounds__(256) void k_rfftW(const float* __restrict__ J, float* __restrict__ F1x, float* __restrict__ F1y){
    int row = blockIdx.x;             // (b*2+f)*256 + h
    int kx = threadIdx.x;
    if (kx < 129){
        const float* rp = J + (size_t)row*256;
        float sc, ss; sincosf((float)kx*TH_, &ss, &sc);
        float pr=1.f, pi=0.f;          // e^{-i th kx w}
        float ar=0.f, ai=0.f;
        for (int w=0; w<256; ++w){
            float v = rp[w];
            ar = fmaf(v, pr, ar);
            ai = fmaf(v, pi, ai);
            float nr = pr*sc + pi*ss;   // * (sc - i ss)
            pi = pi*sc - pr*ss;
            pr = nr;
        }
        int f = (row >> 8) & 1;
        int bh = ((row >> 9) << 8) | (row & 255);
        float2* outp = (float2*)(f ? F1y : F1x) + (size_t)bh*129 + kx;
        *outp = make_float2(ar*(1.f/16.f), ai*(1.f/16.f));
    }
}

// F2[b,ky,kx] = (1/16)( i*fy(ky)*fftH(F1x) + i*fx(kx)*fftH(F1y) )
__global__ __launch_bounds__(256) void k_fftHdiv(const float* __restrict__ F1x, const float* __restrict__ F1y, float* __restrict__ F2){
    int b = blockIdx.x / 129, kx = blockIdx.x % 129;
    int ky = threadIdx.x;
    const float2* px = (const float2*)F1x + (size_t)b*256*129 + kx;
    const float2* py = (const float2*)F1y + (size_t)b*256*129 + kx;
    float sc, ss; sincosf((float)ky*TH_, &ss, &sc);
    float pr=1.f, pi=0.f;              // e^{-i th ky h}
    float xr=0.f,xi=0.f,yr=0.f,yi=0.f;
    for (int h=0; h<256; ++h){
        float2 vx = px[(size_t)h*129];
        float2 vy = py[(size_t)h*129];
        xr += vx.x*pr - vx.y*pi;  xi += vx.x*pi + vx.y*pr;
        yr += vy.x*pr - vy.y*pi;  yi += vy.x*pi + vy.y*pr;
        float nr = pr*sc + pi*ss; pi = pi*sc - pr*ss; pr = nr;
    }
    float fy = (ky < 128)? (float)ky : (float)(ky-256);
    float fx = (kx < 128)? (float)kx : -128.f;
    float dr = -(fy*xi + fx*yi) * (1.f/16.f);
    float di =  (fy*xr + fx*yr) * (1.f/16.f);
    ((float2*)F2)[(size_t)(b*256+ky)*129 + kx] = make_float2(dr, di);
}

// F3[b,h,kx] = (1/16) sum_ky F2 e^{+i th ky h}
__global__ __launch_bounds__(256) void k_ifftH(const float* __restrict__ F2, float* __restrict__ F3){
    int b = blockIdx.x / 129, kx = blockIdx.x % 129;
    int h = threadIdx.x;
    const float2* p2 = (const float2*)F2 + (size_t)b*256*129 + kx;
    float sc, ss; sincosf((float)h*TH_, &ss, &sc);
    float pr=1.f, pi=0.f;
    float arr=0.f, aii=0.f;
    for (int ky=0; ky<256; ++ky){
        float2 v = p2[(size_t)ky*129];
        arr += v.x*pr - v.y*pi;
        aii += v.x*pi + v.y*pr;
        float nr = pr*sc - pi*ss; pi = pi*sc + pr*ss; pr = nr;  // * (sc + i ss)
    }
    ((float2*)F3)[(size_t)(b*256+h)*129 + kx] = make_float2(arr*(1.f/16.f), aii*(1.f/16.f));
}

// dt_rho = -irfftW(F3); write pred rho (softplus10) and dt rho channels
__global__ __launch_bounds__(256) void k_irfftW(const float* __restrict__ F3, const float* __restrict__ st, float* __restrict__ outp){
    int b = blockIdx.x >> 8, h = blockIdx.x & 255;
    int w = threadIdx.x;
    const float2* rp = (const float2*)F3 + (size_t)(b*256+h)*129;
    float sc, ss; sincosf((float)w*TH_, &ss, &sc);
    float2 b0 = rp[0];
    float y = b0.x;
    float pr = sc, pi = ss;            // kx=1 phase e^{+i th w}
    for (int kx=1; kx<128; ++kx){
        float2 v = rp[kx];
        y += 2.f*(v.x*pr - v.y*pi);
        float nr = pr*sc - pi*ss; pi = pi*sc + pr*ss; pr = nr;
    }
    float2 v128 = rp[128];
    y += (w & 1)? -v128.x : v128.x;
    y *= (1.f/16.f);
    float rho = -y;
    int hw = h*256 + w;
    float s0 = st[(size_t)(b*3)*HW + hw];
    float t = 10.f*fmaf(0.05f, rho, s0);
    float sp = fmaxf(t, 0.f) + log1pf(expf(-fabsf(t)));
    outp[(size_t)(b*3)*HW + hw] = 0.1f*sp;
    outp[(size_t)1572864 + (size_t)(b*3)*HW + hw] = rho;
}

__global__ __launch_bounds__(256) void k_final(const float* __restrict__ dtP, const float* __restrict__ st, float* __restrict__ outp){
    int idx = blockIdx.x*256 + threadIdx.x;   // (b*2+c)*HW + hw
    int b = idx >> 17, r = idx & (2*HW-1);
    int c = r >> 16, hw = r & (HW-1);
    float dp = dtP[idx];
    float sv = st[(size_t)(b*3+1+c)*HW + hw];
    outp[(size_t)(b*3+1+c)*HW + hw] = fmaf(0.05f, dp, sv);
    outp[(size_t)1572864 + (size_t)(b*3+1+c)*HW + hw] = dp;
}

extern "C" void kernel_launch(void* const* d_in, const int* in_sizes, int n_in,
                              void* d_out, int out_size, void* d_ws, size_t ws_size,
                              hipStream_t stream){
    const float* state = (const float*)d_in[0];
    const float* lw  = (const float*)d_in[1];
    const float* lb  = (const float*)d_in[2];
    const float* swr = (const float*)d_in[3];
    const float* swi = (const float*)d_in[4];
    const float* pww = (const float*)d_in[5];
    // d_in[6] = pw_b : cancels exactly in InstanceNorm, unused
    const float* fw1 = (const float*)d_in[7];
    const float* fb1 = (const float*)d_in[8];
    const float* fw2 = (const float*)d_in[9];
    const float* fb2 = (const float*)d_in[10];
    const float* qw1 = (const float*)d_in[11];
    const float* qb1 = (const float*)d_in[12];
    const float* qw2 = (const float*)d_in[13];
    const float* qb2 = (const float*)d_in[14];
    float* outp = (float*)d_out;
    float* ws = (float*)d_ws;

    float* x   = ws;                    // 33,554,432 f32
    float* S   = x   + 33554432;        // 16,384
    float* A   = S   + 16384;           // 262,144
    float* CS  = A   + 262144;          // 262,144
    float* J   = CS  + 262144;          // 1,048,576
    float* dtP = J   + 1048576;         // 1,048,576
    float* F1x = dtP + 1048576;         // 528,384
    float* F1y = F1x + 528384;          // 528,384
    float* F2  = F1y + 528384;          // 528,384
    float* F3  = F2  + 528384;          // 528,384
    float* GH  = F3  + 528384;          // 512
    float* T   = J;                     // alias: T (262,144 f32) lives in J's slot,
                                        // dead before k_heads writes J

    hipLaunchKernelGGL(k_tables, dim3(1), dim3(256), 0, stream, GH);
    hipLaunchKernelGGL(k_lift, dim3(2048), dim3(256), 0, stream, state, lw, lb, x);
    for (int l=0; l<4; ++l){
        if (l == 0)
            hipLaunchKernelGGL(k_analysis, dim3(512), dim3(256), 0, stream, x, GH, S);
        else
            hipLaunchKernelGGL(k_analysisT, dim3(512), dim3(256), 0, stream, T, S);
        hipLaunchKernelGGL(k_mixA, dim3(512), dim3(256), 0, stream, S,
                           swr + (size_t)l*1048576, swi + (size_t)l*1048576, A);
        hipLaunchKernelGGL(k_mixB, dim3(512), dim3(256), 0, stream, A, pww + l*4096, CS);
        if (l < 3)
            hipLaunchKernelGGL((k_synth<true>),  dim3(2048), dim3(256), 0, stream, CS, x, GH, T);
        else
            hipLaunchKernelGGL((k_synth<false>), dim3(2048), dim3(256), 0, stream, CS, x, GH, T);
    }
    hipLaunchKernelGGL(k_heads, dim3(2048), dim3(256), 0, stream, x,
                       fw1, fb1, fw2, fb2, qw1, qb1, qw2, qb2, J, dtP);
    hipLaunchKernelGGL(k_rfftW,  dim3(4096), dim3(256), 0, stream, J, F1x, F1y);
    hipLaunchKernelGGL(k_fftHdiv, dim3(1032), dim3(256), 0, stream, F1x, F1y, F2);
    hipLaunchKernelGGL(k_ifftH,  dim3(1032), dim3(256), 0, stream, F2, F3);
    hipLaunchKernelGGL(k_irfftW, dim3(2048), dim3(256), 0, stream, F3, state, outp);
    hipLaunchKernelGGL(k_final,  dim3(4096), dim3(256), 0, stream, dtP, state, outp);
}

// Round 5
// 621.109 us; speedup vs baseline: 1.3595x; 1.0700x over previous
//
#include <hip/hip_runtime.h>
#include <math.h>

#define HW 65536
#define TH_ 0.024543692606170259f  // 2*pi/256

typedef __attribute__((ext_vector_type(8))) short bf16x8;
typedef __attribute__((ext_vector_type(4))) float f32x4;

// Fast gelu: Abramowitz-Stegun 7.1.26 erf, |abs err| ~3e-7.
__device__ __forceinline__ float gelu_f(float v){
    float u = fabsf(v)*0.7071067811865476f;
    float t = __builtin_amdgcn_rcpf(fmaf(0.3275911f, u, 1.0f));
    float p = t*fmaf(t, fmaf(t, fmaf(t, fmaf(t, 1.061405429f, -1.453152027f),
                     1.421413741f), -0.284496736f), 0.254829592f);
    float e = __expf(-u*u);
    float erfu = fmaf(-p, e, 1.0f);
    float er = copysignf(erfu, v);
    return 0.5f*v*(1.0f+er);
}

__device__ __forceinline__ short f2bf(float f){
    union { float f; unsigned u; } v; v.f = f;
    unsigned r = (v.u + 0x7FFF + ((v.u >> 16) & 1)) >> 16;   // RNE
    return (short)r;
}
__device__ __forceinline__ float bf2f(short s){
    union { float f; unsigned u; } v; v.u = ((unsigned)(unsigned short)s) << 16;
    return v.f;
}

// v_cvt_pk_bf16_f32: D.lo = bf16(S0), D.hi = bf16(S1)
__device__ __forceinline__ unsigned cvt_pk_bf16(float lo, float hi){
    unsigned r;
    asm("v_cvt_pk_bf16_f32 %0, %1, %2" : "=v"(r) : "v"(lo), "v"(hi));
    return r;
}

union U8 { bf16x8 v; unsigned u[4]; };

// split 8 floats -> hi/lo bf16x8 using packed converts (~3 ops/element)
__device__ __forceinline__ void split8(const float* f, bf16x8& H, bf16x8& L){
    U8 h, l;
    #pragma unroll
    for (int p=0;p<4;++p){
        float a = f[2*p], b = f[2*p+1];
        unsigned hp = cvt_pk_bf16(a, b);
        union { unsigned u; float fl; } ua, ub;
        ua.u = hp << 16; ub.u = hp & 0xffff0000u;
        h.u[p] = hp;
        l.u[p] = cvt_pk_bf16(a - ua.fl, b - ub.fl);
    }
    H = h.v; L = l.v;
}

// GH[h] = sum_{ky<16} e^{-2pi i ky h /256}
__global__ void k_tables(float* __restrict__ GH){
    int h = threadIdx.x;
    double gr = 0.0, gi = 0.0;
    for (int ky=0; ky<16; ++ky){
        double a = -2.0*3.14159265358979323846*(double)(ky*h)/256.0;
        gr += cos(a); gi += sin(a);
    }
    GH[2*h] = (float)gr; GH[2*h+1] = (float)gi;
}

// Precompute split-bf16 W1 fragments for k_heads (manual f2bf: one-time, safe).
// frag idx = ((ph*4+n)*2+ks)*64 + lane ; hi at [idx], lo at [1024+idx]
__global__ __launch_bounds__(256) void k_prepW(const float* __restrict__ fw1, const float* __restrict__ qw1,
                                               float* __restrict__ Wf){
    int t = blockIdx.x*256 + threadIdx.x;       // 1024 total
    int lane = t & 63, ks = (t>>6)&1, n = (t>>7)&3, ph = (t>>9)&1;
    int l15 = lane & 15, lg = lane >> 4;
    const float* w1p = ph ? qw1 : fw1;
    int oc = n*16 + l15;
    U8 h, l;
    #pragma unroll
    for (int p=0;p<4;++p){
        float a = w1p[oc*64 + ks*32 + lg*8 + 2*p];
        float b = w1p[oc*64 + ks*32 + lg*8 + 2*p+1];
        short ha = f2bf(a), hb = f2bf(b);
        h.u[p] = ((unsigned)(unsigned short)ha) | (((unsigned)(unsigned short)hb)<<16);
        short la = f2bf(a - bf2f(ha)), lb = f2bf(b - bf2f(hb));
        l.u[p] = ((unsigned)(unsigned short)la) | (((unsigned)(unsigned short)lb)<<16);
    }
    int idx = ((ph*4+n)*2+ks)*64 + lane;
    ((bf16x8*)Wf)[idx] = h.v;
    ((bf16x8*)Wf)[1024 + idx] = l.v;
}

// x[b,c,hw] = gelu(sum_i lw[c,i]*state[b,i,hw] + lb[c])
__global__ __launch_bounds__(256) void k_lift(const float* __restrict__ st, const float* __restrict__ lw,
                                              const float* __restrict__ lb, float* __restrict__ x){
    int p = blockIdx.x*256 + threadIdx.x;
    int b = p >> 16, hw = p & (HW-1);
    float s0 = st[(b*3+0)*HW + hw];
    float s1 = st[(b*3+1)*HW + hw];
    float s2 = st[(b*3+2)*HW + hw];
    float* xp = x + (size_t)b*64*HW + hw;
    for (int c=0;c<64;++c){
        float v = fmaf(lw[c*3], s0, fmaf(lw[c*3+1], s1, fmaf(lw[c*3+2], s2, lb[c])));
        xp[(size_t)c*HW] = gelu_f(v);
    }
}

// Layer-0 analysis (reads x): S[b,i,k] = (1/256) sum_w e^{-i th k w} * (sum_h GH[h]*x[b,i,h,w])
__global__ __launch_bounds__(256) void k_analysis(const float* __restrict__ x, const float* __restrict__ GH,
                                                  float* __restrict__ S){
    int b = blockIdx.x >> 6, i = blockIdx.x & 63;
    int w = threadIdx.x;
    const float* xp = x + ((size_t)(b*64+i))*HW + w;
    float Tr = 0.f, Ti = 0.f;
    #pragma unroll 4
    for (int h=0; h<256; ++h){
        float v = xp[h*256];
        Tr = fmaf(GH[2*h],   v, Tr);
        Ti = fmaf(GH[2*h+1], v, Ti);
    }
    float c1, s1; sincosf((float)w * TH_, &s1, &c1);
    float Sr[16], Si[16];
    float ck = 1.f, sk = 0.f;
    #pragma unroll
    for (int k=0;k<16;++k){
        Sr[k] = Tr*ck + Ti*sk;     // T * e^{-i th k w}
        Si[k] = Ti*ck - Tr*sk;
        float nc = ck*c1 - sk*s1;
        sk = ck*s1 + sk*c1;
        ck = nc;
    }
    #pragma unroll
    for (int k=0;k<16;++k){
        #pragma unroll
        for (int off=32; off; off>>=1){
            Sr[k] += __shfl_xor(Sr[k], off, 64);
            Si[k] += __shfl_xor(Si[k], off, 64);
        }
    }
    __shared__ float red[4][32];
    int wv = threadIdx.x >> 6, ln = threadIdx.x & 63;
    if (ln == 0){
        #pragma unroll
        for (int k=0;k<16;++k){ red[wv][2*k] = Sr[k]; red[wv][2*k+1] = Si[k]; }
    }
    __syncthreads();
    if (threadIdx.x < 32){
        float v = red[0][threadIdx.x]+red[1][threadIdx.x]+red[2][threadIdx.x]+red[3][threadIdx.x];
        S[(b*64+i)*32 + threadIdx.x] = v * (1.0f/256.0f);
    }
}

// Layers 1-3: analysis from fused T[b,i,w] (1 MB) instead of re-reading x (134 MB)
__global__ __launch_bounds__(256) void k_analysisT(const float* __restrict__ T, float* __restrict__ S){
    int bi = blockIdx.x;               // b*64+i
    int w = threadIdx.x;
    float2 t = ((const float2*)T)[bi*256 + w];
    float Tr = t.x, Ti = t.y;
    float c1, s1; sincosf((float)w * TH_, &s1, &c1);
    float Sr[16], Si[16];
    float ck = 1.f, sk = 0.f;
    #pragma unroll
    for (int k=0;k<16;++k){
        Sr[k] = Tr*ck + Ti*sk;
        Si[k] = Ti*ck - Tr*sk;
        float nc = ck*c1 - sk*s1;
        sk = ck*s1 + sk*c1;
        ck = nc;
    }
    #pragma unroll
    for (int k=0;k<16;++k){
        #pragma unroll
        for (int off=32; off; off>>=1){
            Sr[k] += __shfl_xor(Sr[k], off, 64);
            Si[k] += __shfl_xor(Si[k], off, 64);
        }
    }
    __shared__ float red[4][32];
    int wv = threadIdx.x >> 6, ln = threadIdx.x & 63;
    if (ln == 0){
        #pragma unroll
        for (int k=0;k<16;++k){ red[wv][2*k] = Sr[k]; red[wv][2*k+1] = Si[k]; }
    }
    __syncthreads();
    if (threadIdx.x < 32){
        float v = red[0][threadIdx.x]+red[1][threadIdx.x]+red[2][threadIdx.x]+red[3][threadIdx.x];
        S[bi*32 + threadIdx.x] = v * (1.0f/256.0f);
    }
}

// A[b,j,km] = sum_i S[b,i,k] * (wr + i wi)[i,j,km]
__global__ __launch_bounds__(256) void k_mixA(const float* __restrict__ S, const float* __restrict__ wr,
                                              const float* __restrict__ wi, float* __restrict__ A){
    int j = blockIdx.x >> 3, b = blockIdx.x & 7;
    __shared__ float sS[2048];
    for (int t=threadIdx.x; t<2048; t+=256) sS[t] = S[b*2048 + t];
    __syncthreads();
    int km = threadIdx.x, k = km >> 4;
    float ar = 0.f, ai = 0.f;
    const float* wrp = wr + j*256 + km;
    const float* wip = wi + j*256 + km;
    #pragma unroll 4
    for (int i=0;i<64;++i){
        float wrv = wrp[i*16384];
        float wiv = wip[i*16384];
        float2 sv = ((const float2*)sS)[i*16 + k];
        ar += sv.x*wrv - sv.y*wiv;
        ai += sv.x*wiv + sv.y*wrv;
    }
    ((float2*)A)[(b*64 + j)*256 + km] = make_float2(ar, ai);
}

// c = sum_j pw[o,j]*A[b,j,km]; Parseval instance-norm stats; CS = c * inv_sigma * alpha(m) / 256
__global__ __launch_bounds__(256) void k_mixB(const float* __restrict__ A, const float* __restrict__ pw,
                                              float* __restrict__ CS){
    int b = blockIdx.x >> 6, o = blockIdx.x & 63;
    int km = threadIdx.x, m = km & 15;
    const float2* Ap = (const float2*)A + b*64*256 + km;
    const float* pwp = pw + o*64;
    float cr=0.f, ci=0.f;
    #pragma unroll 4
    for (int j=0;j<64;++j){
        float p = pwp[j];
        float2 a = Ap[j*256];
        cr = fmaf(p, a.x, cr);
        ci = fmaf(p, a.y, ci);
    }
    float aw = (m==0)? 1.f : 4.f;          // alpha(m)^2
    float s = (km==0)? 0.f : aw*(cr*cr + ci*ci);
    #pragma unroll
    for (int off=32; off; off>>=1) s += __shfl_xor(s, off, 64);
    __shared__ float rsum[4];
    __shared__ float sinv;
    if ((threadIdx.x & 63) == 0) rsum[threadIdx.x>>6] = s;
    __syncthreads();
    if (threadIdx.x == 0){
        float var = (rsum[0]+rsum[1]+rsum[2]+rsum[3]) * (1.0f/131072.0f); // /(2*H*W)
        sinv = rsqrtf(var + 1e-5f);
    }
    __syncthreads();
    float alpha = (m==0)? 1.f : 2.f;
    float sc = sinv * alpha * (1.0f/256.0f);
    if (km == 0) cr = 0.f;                 // remove mean (DC real part)
    ((float2*)CS)[blockIdx.x*256 + km] = make_float2(cr*sc, ci*sc);
}

// x[b,o,h,w] = gelu( sum_k Re( V_k(w) e^{+i th k h} ) ) + x[b,o,h,w]
// Phase A: V[k,w] computed cooperatively (thread (w,kq) does 4 k's), shared via LDS
// (removes the 4x per-wave redundancy of the old per-thread 16k x 16m sum).
// EMIT_T: also accumulate T[b,o,w] = sum_h GH[h]*x_new[h,w] for next layer's analysis.
template<bool EMIT_T>
__global__ __launch_bounds__(256) void k_synth(const float* __restrict__ CS, float* __restrict__ x,
                                               const float* __restrict__ GH, float* __restrict__ T){
    int bo = blockIdx.x >> 2, wt = blockIdx.x & 3;
    int lane = threadIdx.x & 63, wv = threadIdx.x >> 6;
    int w = wt*64 + lane;
    __shared__ float sGH[512];
    __shared__ float2 sV[16][64];
    if (EMIT_T){
        sGH[threadIdx.x] = GH[threadIdx.x];
        sGH[256+threadIdx.x] = GH[256+threadIdx.x];
    }
    const float2* cs = (const float2*)CS + bo*256;
    {   // phase A: this thread computes V[k] for k in [4*wv, 4*wv+4) at its w
        float Vr[4] = {0.f,0.f,0.f,0.f}, Vi[4] = {0.f,0.f,0.f,0.f};
        float stepc, steps; sincosf((float)w*TH_, &steps, &stepc);
        float pc = 1.f, ps = 0.f;          // e^{+i m th w}
        for (int m=0;m<16;++m){
            #pragma unroll
            for (int kk=0;kk<4;++kk){
                float2 a = cs[(wv*4+kk)*16 + m];
                Vr[kk] += a.x*pc - a.y*ps;
                Vi[kk] += a.x*ps + a.y*pc;
            }
            float nc = pc*stepc - ps*steps;
            ps = pc*steps + ps*stepc;
            pc = nc;
        }
        #pragma unroll
        for (int kk=0;kk<4;++kk) sV[wv*4+kk][lane] = make_float2(Vr[kk], Vi[kk]);
    }
    __syncthreads();
    int h0 = wv*16;
    float rc[16], rs[16], qr[16], qi[16];
    #pragma unroll
    for (int k=0;k<16;++k){
        float2 v = sV[k][lane];
        sincosf((float)k*TH_, &rs[k], &rc[k]);
        float c0, s0; sincosf((float)(k*h0)*TH_, &s0, &c0);
        qr[k] = v.x*c0 - v.y*s0;       // q = V * e^{+i th k h0}
        qi[k] = v.x*s0 + v.y*c0;
    }
    float* xp = x + ((size_t)bo << 16);
    float Tr = 0.f, Ti = 0.f;
    for (int i=0;i<16;++i){
        float y0=0.f,y1=0.f,y2=0.f,y3=0.f;
        #pragma unroll
        for (int k=0;k<16;++k){
            float re = qr[k], im = qi[k];
            y0 += re;                                   // h
            if ((k&3)==0)      { y1 += re; y2 += re; y3 += re; }   // *i^k, *(-1)^k, *(-i)^k
            else if ((k&3)==1) { y1 -= im; y2 -= re; y3 += im; }
            else if ((k&3)==2) { y1 -= re; y2 += re; y3 -= re; }
            else               { y1 += im; y2 -= re; y3 -= im; }
        }
        #pragma unroll
        for (int k=1;k<16;++k){
            float nr = qr[k]*rc[k] - qi[k]*rs[k];
            qi[k]    = qr[k]*rs[k] + qi[k]*rc[k];
            qr[k] = nr;
        }
        int p0 = (h0+i)*256 + w;
        float x0 = xp[p0], x1 = xp[p0+16384], x2 = xp[p0+32768], x3 = xp[p0+49152];
        float n0 = gelu_f(y0) + x0;
        float n1 = gelu_f(y1) + x1;
        float n2 = gelu_f(y2) + x2;
        float n3 = gelu_f(y3) + x3;
        xp[p0]       = n0;
        xp[p0+16384] = n1;
        xp[p0+32768] = n2;
        xp[p0+49152] = n3;
        if (EMIT_T){
            int h = h0+i;
            Tr = fmaf(sGH[2*h],     n0, Tr);  Ti = fmaf(sGH[2*h+1],     n0, Ti);
            Tr = fmaf(sGH[2*h+128], n1, Tr);  Ti = fmaf(sGH[2*h+129],   n1, Ti);
            Tr = fmaf(sGH[2*h+256], n2, Tr);  Ti = fmaf(sGH[2*h+257],   n2, Ti);
            Tr = fmaf(sGH[2*h+384], n3, Tr);  Ti = fmaf(sGH[2*h+385],   n3, Ti);
        }
    }
    if (EMIT_T){
        __shared__ float2 tpart[4][64];
        tpart[wv][lane] = make_float2(Tr, Ti);
        __syncthreads();
        if (wv == 0){
            float2 a = tpart[0][lane], b2 = tpart[1][lane];
            float2 c = tpart[2][lane], d = tpart[3][lane];
            ((float2*)T)[bo*256 + w] = make_float2(a.x+b2.x+c.x+d.x, a.y+b2.y+c.y+d.y);
        }
    }
}

// MFMA heads: A-frags via packed converts; B-frags precomputed by k_prepW.
__global__ __launch_bounds__(256) void k_heads(const float* __restrict__ x,
        const float* __restrict__ Wf,
        const float* __restrict__ fb1, const float* __restrict__ fw2, const float* __restrict__ fb2,
        const float* __restrict__ qb1, const float* __restrict__ qw2, const float* __restrict__ qb2,
        float* __restrict__ J, float* __restrict__ dtP){
    int wv = threadIdx.x >> 6, lane = threadIdx.x & 63;
    int l15 = lane & 15, lg = lane >> 4;
    int px0 = blockIdx.x*256 + wv*64;
    int b = px0 >> 16;
    int hwbase = px0 & (HW-1);
    const float* xb = x + (size_t)b*64*HW;
    const bf16x8* WfH = (const bf16x8*)Wf;

    // ---- A fragments: 4 M-tiles x 2 k-steps, hi/lo bf16 via cvt_pk
    bf16x8 Ahi[4][2], Alo[4][2];
    #pragma unroll
    for (int mt=0; mt<4; ++mt){
        int px = hwbase + mt*16 + l15;
        #pragma unroll
        for (int ks=0; ks<2; ++ks){
            float f[8];
            #pragma unroll
            for (int j=0; j<8; ++j)
                f[j] = xb[(size_t)((ks*32 + lg*8 + j))*HW + px];
            split8(f, Ahi[mt][ks], Alo[mt][ks]);
        }
    }

    #pragma unroll
    for (int ph=0; ph<2; ++ph){
        const float* b1p = ph ? qb1 : fb1;
        const float* w2p = ph ? qw2 : fw2;
        const float* b2p = ph ? qb2 : fb2;
        float* outp = ph ? dtP : J;

        float p0[16], p1[16];
        #pragma unroll
        for (int t=0;t<16;++t){ p0[t]=0.f; p1[t]=0.f; }

        for (int n=0; n<4; ++n){
            int oc = n*16 + l15;
            bf16x8 Bhi[2], Blo[2];
            #pragma unroll
            for (int ks=0; ks<2; ++ks){
                int idx = ((ph*4+n)*2+ks)*64 + lane;
                Bhi[ks] = WfH[idx];
                Blo[ks] = WfH[1024 + idx];
            }
            float bias = b1p[oc];
            float w2a = w2p[oc], w2b = w2p[64+oc];
            #pragma unroll
            for (int mt=0; mt<4; ++mt){
                f32x4 d = {0.f,0.f,0.f,0.f};
                #pragma unroll
                for (int ks=0; ks<2; ++ks){
                    d = __builtin_amdgcn_mfma_f32_16x16x32_bf16(Ahi[mt][ks], Bhi[ks], d, 0,0,0);
                    d = __builtin_amdgcn_mfma_f32_16x16x32_bf16(Ahi[mt][ks], Blo[ks], d, 0,0,0);
                    d = __builtin_amdgcn_mfma_f32_16x16x32_bf16(Alo[mt][ks], Bhi[ks], d, 0,0,0);
                }
                #pragma unroll
                for (int r=0;r<4;++r){
                    float g = gelu_f(d[r] + bias);
                    p0[mt*4+r] = fmaf(w2a, g, p0[mt*4+r]);
                    p1[mt*4+r] = fmaf(w2b, g, p1[mt*4+r]);
                }
            }
        }
        #pragma unroll
        for (int t=0;t<16;++t){
            #pragma unroll
            for (int off=1; off<16; off<<=1){
                p0[t] += __shfl_xor(p0[t], off, 64);
                p1[t] += __shfl_xor(p1[t], off, 64);
            }
        }
        float bo0 = b2p[0], bo1 = b2p[1];
        if (l15 == 0){
            float* plane = outp + ((size_t)(b*2 + 0))*HW;
            #pragma unroll
            for (int mt=0; mt<4; ++mt){
                int px = hwbase + mt*16 + lg*4;
                float4 v; v.x=p0[mt*4+0]+bo0; v.y=p0[mt*4+1]+bo0; v.z=p0[mt*4+2]+bo0; v.w=p0[mt*4+3]+bo0;
                *(float4*)(plane + px) = v;
            }
        } else if (l15 == 1){
            float* plane = outp + ((size_t)(b*2 + 1))*HW;
            #pragma unroll
            for (int mt=0; mt<4; ++mt){
                int px = hwbase + mt*16 + lg*4;
                float4 v; v.x=p1[mt*4+0]+bo1; v.y=p1[mt*4+1]+bo1; v.z=p1[mt*4+2]+bo1; v.w=p1[mt*4+3]+bo1;
                *(float4*)(plane + px) = v;
            }
        }
    }
}

// F1[b,f,h,kx] = (1/16) sum_w J[row,w] e^{-i th kx w}   (129 active lanes, 3 waves)
__global__ __launch_bounds__(192) void k_rfftW(const float* __restrict__ J, float* __restrict__ F1x, float* __restrict__ F1y){
    int row = blockIdx.x;             // (b*2+f)*256 + h
    int kx = threadIdx.x;
    if (kx < 129){
        const float* rp = J + (size_t)row*256;
        float sc, ss; sincosf((float)kx*TH_, &ss, &sc);
        float pr=1.f, pi=0.f;          // e^{-i th kx w}
        float ar=0.f, ai=0.f;
        for (int w=0; w<256; ++w){
            float v = rp[w];
            ar = fmaf(v, pr, ar);
            ai = fmaf(v, pi, ai);
            float nr = pr*sc + pi*ss;   // * (sc - i ss)
            pi = pi*sc - pr*ss;
            pr = nr;
        }
        int f = (row >> 8) & 1;
        int bh = ((row >> 9) << 8) | (row & 255);
        float2* outp = (float2*)(f ? F1y : F1x) + (size_t)bh*129 + kx;
        *outp = make_float2(ar*(1.f/16.f), ai*(1.f/16.f));
    }
}

// F2[b,ky,kx] = (1/16)( i*fy(ky)*fftH(F1x) + i*fx(kx)*fftH(F1y) )
__global__ __launch_bounds__(256) void k_fftHdiv(const float* __restrict__ F1x, const float* __restrict__ F1y, float* __restrict__ F2){
    int b = blockIdx.x / 129, kx = blockIdx.x % 129;
    int ky = threadIdx.x;
    const float2* px = (const float2*)F1x + (size_t)b*256*129 + kx;
    const float2* py = (const float2*)F1y + (size_t)b*256*129 + kx;
    float sc, ss; sincosf((float)ky*TH_, &ss, &sc);
    float pr=1.f, pi=0.f;              // e^{-i th ky h}
    float xr=0.f,xi=0.f,yr=0.f,yi=0.f;
    for (int h=0; h<256; ++h){
        float2 vx = px[(size_t)h*129];
        float2 vy = py[(size_t)h*129];
        xr += vx.x*pr - vx.y*pi;  xi += vx.x*pi + vx.y*pr;
        yr += vy.x*pr - vy.y*pi;  yi += vy.x*pi + vy.y*pr;
        float nr = pr*sc + pi*ss; pi = pi*sc - pr*ss; pr = nr;
    }
    float fy = (ky < 128)? (float)ky : (float)(ky-256);
    float fx = (kx < 128)? (float)kx : -128.f;
    float dr = -(fy*xi + fx*yi) * (1.f/16.f);
    float di =  (fy*xr + fx*yr) * (1.f/16.f);
    ((float2*)F2)[(size_t)(b*256+ky)*129 + kx] = make_float2(dr, di);
}

// F3[b,h,kx] = (1/16) sum_ky F2 e^{+i th ky h}
__global__ __launch_bounds__(256) void k_ifftH(const float* __restrict__ F2, float* __restrict__ F3){
    int b = blockIdx.x / 129, kx = blockIdx.x % 129;
    int h = threadIdx.x;
    const float2* p2 = (const float2*)F2 + (size_t)b*256*129 + kx;
    float sc, ss; sincosf((float)h*TH_, &ss, &sc);
    float pr=1.f, pi=0.f;
    float arr=0.f, aii=0.f;
    for (int ky=0; ky<256; ++ky){
        float2 v = p2[(size_t)ky*129];
        arr += v.x*pr - v.y*pi;
        aii += v.x*pi + v.y*pr;
        float nr = pr*sc - pi*ss; pi = pi*sc + pr*ss; pr = nr;  // * (sc + i ss)
    }
    ((float2*)F3)[(size_t)(b*256+h)*129 + kx] = make_float2(arr*(1.f/16.f), aii*(1.f/16.f));
}

// dt_rho = -irfftW(F3); write pred rho (softplus10) and dt rho channels
__global__ __launch_bounds__(256) void k_irfftW(const float* __restrict__ F3, const float* __restrict__ st, float* __restrict__ outp){
    int b = blockIdx.x >> 8, h = blockIdx.x & 255;
    int w = threadIdx.x;
    const float2* rp = (const float2*)F3 + (size_t)(b*256+h)*129;
    float sc, ss; sincosf((float)w*TH_, &ss, &sc);
    float2 b0 = rp[0];
    float y = b0.x;
    float pr = sc, pi = ss;            // kx=1 phase e^{+i th w}
    for (int kx=1; kx<128; ++kx){
        float2 v = rp[kx];
        y += 2.f*(v.x*pr - v.y*pi);
        float nr = pr*sc - pi*ss; pi = pi*sc + pr*ss; pr = nr;
    }
    float2 v128 = rp[128];
    y += (w & 1)? -v128.x : v128.x;
    y *= (1.f/16.f);
    float rho = -y;
    int hw = h*256 + w;
    float s0 = st[(size_t)(b*3)*HW + hw];
    float t = 10.f*fmaf(0.05f, rho, s0);
    float sp = fmaxf(t, 0.f) + log1pf(expf(-fabsf(t)));
    outp[(size_t)(b*3)*HW + hw] = 0.1f*sp;
    outp[(size_t)1572864 + (size_t)(b*3)*HW + hw] = rho;
}

__global__ __launch_bounds__(256) void k_final(const float* __restrict__ dtP, const float* __restrict__ st, float* __restrict__ outp){
    int idx = blockIdx.x*256 + threadIdx.x;   // (b*2+c)*HW + hw
    int b = idx >> 17, r = idx & (2*HW-1);
    int c = r >> 16, hw = r & (HW-1);
    float dp = dtP[idx];
    float sv = st[(size_t)(b*3+1+c)*HW + hw];
    outp[(size_t)(b*3+1+c)*HW + hw] = fmaf(0.05f, dp, sv);
    outp[(size_t)1572864 + (size_t)(b*3+1+c)*HW + hw] = dp;
}

extern "C" void kernel_launch(void* const* d_in, const int* in_sizes, int n_in,
                              void* d_out, int out_size, void* d_ws, size_t ws_size,
                              hipStream_t stream){
    const float* state = (const float*)d_in[0];
    const float* lw  = (const float*)d_in[1];
    const float* lb  = (const float*)d_in[2];
    const float* swr = (const float*)d_in[3];
    const float* swi = (const float*)d_in[4];
    const float* pww = (const float*)d_in[5];
    // d_in[6] = pw_b : cancels exactly in InstanceNorm, unused
    const float* fw1 = (const float*)d_in[7];
    const float* fb1 = (const float*)d_in[8];
    const float* fw2 = (const float*)d_in[9];
    const float* fb2 = (const float*)d_in[10];
    const float* qw1 = (const float*)d_in[11];
    const float* qb1 = (const float*)d_in[12];
    const float* qw2 = (const float*)d_in[13];
    const float* qb2 = (const float*)d_in[14];
    float* outp = (float*)d_out;
    float* ws = (float*)d_ws;

    float* x   = ws;                    // 33,554,432 f32
    float* S   = x   + 33554432;        // 16,384
    float* A   = S   + 16384;           // 262,144
    float* CS  = A   + 262144;          // 262,144
    float* J   = CS  + 262144;          // 1,048,576
    float* dtP = J   + 1048576;         // 1,048,576
    float* F1x = dtP + 1048576;         // 528,384
    float* F1y = F1x + 528384;          // 528,384
    float* F2  = F1y + 528384;          // 528,384
    float* F3  = F2  + 528384;          // 528,384
    float* GH  = F3  + 528384;          // 512
    float* Wf  = GH  + 512;             // 8,192 (2048 bf16x8 frags)
    float* T   = J;                     // alias: T dead before k_heads writes J

    hipLaunchKernelGGL(k_tables, dim3(1), dim3(256), 0, stream, GH);
    hipLaunchKernelGGL(k_prepW,  dim3(4), dim3(256), 0, stream, fw1, qw1, Wf);
    hipLaunchKernelGGL(k_lift, dim3(2048), dim3(256), 0, stream, state, lw, lb, x);
    for (int l=0; l<4; ++l){
        if (l == 0)
            hipLaunchKernelGGL(k_analysis, dim3(512), dim3(256), 0, stream, x, GH, S);
        else
            hipLaunchKernelGGL(k_analysisT, dim3(512), dim3(256), 0, stream, T, S);
        hipLaunchKernelGGL(k_mixA, dim3(512), dim3(256), 0, stream, S,
                           swr + (size_t)l*1048576, swi + (size_t)l*1048576, A);
        hipLaunchKernelGGL(k_mixB, dim3(512), dim3(256), 0, stream, A, pww + l*4096, CS);
        if (l < 3)
            hipLaunchKernelGGL((k_synth<true>),  dim3(2048), dim3(256), 0, stream, CS, x, GH, T);
        else
            hipLaunchKernelGGL((k_synth<false>), dim3(2048), dim3(256), 0, stream, CS, x, GH, T);
    }
    hipLaunchKernelGGL(k_heads, dim3(2048), dim3(256), 0, stream, x,
                       Wf, fb1, fw2, fb2, qb1, qw2, qb2, J, dtP);
    hipLaunchKernelGGL(k_rfftW,  dim3(4096), dim3(192), 0, stream, J, F1x, F1y);
    hipLaunchKernelGGL(k_fftHdiv, dim3(1032), dim3(256), 0, stream, F1x, F1y, F2);
    hipLaunchKernelGGL(k_ifftH,  dim3(1032), dim3(256), 0, stream, F2, F3);
    hipLaunchKernelGGL(k_irfftW, dim3(2048), dim3(256), 0, stream, F3, state, outp);
    hipLaunchKernelGGL(k_final,  dim3(4096), dim3(256), 0, stream, dtP, state, outp);
}